// Round 11
// baseline (219.941 us; speedup 1.0000x reference)
//
#include <hip/hip_runtime.h>
#include <math.h>

#define B_ 2
#define T_ 2048
#define E_ 1024
#define H_ 16
#define D_ 64
#define M_ (B_ * T_)                       // 4096
#define LAMBDA_INIT_F 0.4707130183435842f  // 0.8 - 0.6*exp(-0.6)
#define EPS_ 1e-5f
#define QSCALE_LOG2E 0.18033688011112042f  // 0.125 * log2(e)

typedef __attribute__((ext_vector_type(8))) short short8;
typedef __attribute__((ext_vector_type(4))) float f32x4;

// ---------- bf16 helpers ----------
__device__ __forceinline__ unsigned short f2bf(float f) {
    union { float f; unsigned int i; } x;
    x.f = f;
    unsigned int lsb = (x.i >> 16) & 1u;
    x.i += 0x7fffu + lsb;  // round-to-nearest-even
    return (unsigned short)(x.i >> 16);
}
// pack two f32 -> two bf16 (round via +0x8000, take high halves); a=low short, b=high short
__device__ __forceinline__ unsigned int pkbf(float a, float b) {
    union { float f; unsigned int u; } x, y;
    x.f = a; y.f = b;
    return __builtin_amdgcn_perm(y.u + 0x8000u, x.u + 0x8000u, 0x07060302);
}
// pack lo16(x),lo16(y) -> one dword (x low, y high); and hi16 variant. Pure v_perm.
__device__ __forceinline__ unsigned int pklo(unsigned int x, unsigned int y) {
    return __builtin_amdgcn_perm(y, x, 0x05040100u);
}
__device__ __forceinline__ unsigned int pkhi(unsigned int x, unsigned int y) {
    return __builtin_amdgcn_perm(y, x, 0x07060302u);
}

__device__ __forceinline__ float fexp2(float x) {
#if __has_builtin(__builtin_amdgcn_exp2f)
    return __builtin_amdgcn_exp2f(x);
#else
    return exp2f(x);
#endif
}

// ---------- bulk f32 -> bf16 conversion (acts + weights), one launch ----------
__global__ __launch_bounds__(256) void conv_kernel(
    const float* __restrict__ ny, const float* __restrict__ x, const float* __restrict__ w0,
    const float* __restrict__ w1, const float* __restrict__ w2, const float* __restrict__ w3,
    const float* __restrict__ w4, const float* __restrict__ w5, unsigned short* __restrict__ nyb,
    unsigned short* __restrict__ xb, unsigned short* __restrict__ wb0,
    unsigned short* __restrict__ wb1, unsigned short* __restrict__ wb2,
    unsigned short* __restrict__ wb3, unsigned short* __restrict__ wb4,
    unsigned short* __restrict__ wb5) {
    const float* src;
    unsigned short* dst;
    int n4;
    switch (blockIdx.y) {
        case 0: src = ny; dst = nyb; n4 = (M_ * E_) / 4; break;
        case 1: src = x;  dst = xb;  n4 = (M_ * E_) / 4; break;
        case 2: src = w0; dst = wb0; n4 = (E_ * E_) / 4; break;
        case 3: src = w1; dst = wb1; n4 = (E_ * E_) / 4; break;
        case 4: src = w2; dst = wb2; n4 = (E_ * E_) / 4; break;
        case 5: src = w3; dst = wb3; n4 = (E_ * E_) / 4; break;
        case 6: src = w4; dst = wb4; n4 = (E_ * E_) / 4; break;
        default: src = w5; dst = wb5; n4 = (E_ * E_) / 4; break;
    }
    for (int i = blockIdx.x * 256 + threadIdx.x; i < n4; i += 1024 * 256) {
        float4 f = ((const float4*)src)[i];
        uint2 o;
        o.x = pkbf(f.x, f.y);
        o.y = pkbf(f.z, f.w);
        ((uint2*)dst)[i] = o;
    }
}

// ---------- MFMA GEMM core (bf16 inputs, one-step register prefetch) ----------
__device__ __forceinline__ void mfma_gemm_body_b16(unsigned short* Als, unsigned short* Bls,
                                                   const unsigned short* Ab,
                                                   const unsigned short* Wb, int mBase, int nBase,
                                                   int tid, f32x4 acc[4][4]) {
    const int lane = tid & 63;
    const int wv = tid >> 6;
    const int wm = wv >> 1, wn = wv & 1;
    const int col = lane & 15;
    const int quad = lane >> 4;
    const int row = tid >> 1;  // 0..127 staging row
    const int half = tid & 1;  // k-half: cols half*16..+16

    const size_t aoff = (size_t)(mBase + row) * E_ + half * 16;
    const size_t woff = (size_t)(nBase + row) * E_ + half * 16;

    uint4 wa0 = ((const uint4*)(Ab + aoff))[0];
    uint4 wa1 = ((const uint4*)(Ab + aoff))[1];
    uint4 wb0 = ((const uint4*)(Wb + woff))[0];
    uint4 wb1 = ((const uint4*)(Wb + woff))[1];

    for (int k0 = 0; k0 < E_; k0 += 32) {
        __syncthreads();  // previous step's readers done
        *(uint4*)&Als[row * 40 + half * 16] = wa0;
        *(uint4*)&Als[row * 40 + half * 16 + 8] = wa1;
        *(uint4*)&Bls[row * 40 + half * 16] = wb0;
        *(uint4*)&Bls[row * 40 + half * 16 + 8] = wb1;
        __syncthreads();
        if (k0 + 32 < E_) {  // prefetch next tile under this tile's compute
            wa0 = ((const uint4*)(Ab + aoff + k0 + 32))[0];
            wa1 = ((const uint4*)(Ab + aoff + k0 + 32))[1];
            wb0 = ((const uint4*)(Wb + woff + k0 + 32))[0];
            wb1 = ((const uint4*)(Wb + woff + k0 + 32))[1];
        }

        short8 bf[4];
#pragma unroll
        for (int tn = 0; tn < 4; ++tn)
            bf[tn] = *(const short8*)&Bls[(wn * 64 + tn * 16 + col) * 40 + quad * 8];
#pragma unroll
        for (int tm = 0; tm < 4; ++tm) {
            short8 af = *(const short8*)&Als[(wm * 64 + tm * 16 + col) * 40 + quad * 8];
#pragma unroll
            for (int tn = 0; tn < 4; ++tn)
                acc[tm][tn] =
                    __builtin_amdgcn_mfma_f32_16x16x32_bf16(af, bf[tn], acc[tm][tn], 0, 0, 0);
        }
    }
}

// ---------- generic GEMM core (f32 fallback paths, original structure) ----------
template <bool AB, bool WB>
__device__ __forceinline__ void mfma_gemm_body(unsigned short* Als, unsigned short* Bls,
                                               const unsigned short* Ab, const float* Af,
                                               const unsigned short* Wb, const float* Wf,
                                               int mBase, int nBase, int tid, f32x4 acc[4][4]) {
    const int lane = tid & 63;
    const int wv = tid >> 6;
    const int wm = wv >> 1, wn = wv & 1;
    const int col = lane & 15;
    const int quad = lane >> 4;
    const int row = tid >> 1;  // 0..127 staging row
    const int half = tid & 1;  // k-half: cols half*16..+16

    const size_t aoff = (size_t)(mBase + row) * E_ + half * 16;
    const size_t woff = (size_t)(nBase + row) * E_ + half * 16;

    for (int k0 = 0; k0 < E_; k0 += 32) {
        uint4 wa0, wa1, wb0, wb1;
        if (AB) {
            const uint4* s = (const uint4*)(Ab + aoff + k0);
            wa0 = s[0];
            wa1 = s[1];
        } else {
            const float4* s = (const float4*)(Af + aoff + k0);
            float4 f0 = s[0], f1 = s[1], f2 = s[2], f3 = s[3];
            wa0.x = pkbf(f0.x, f0.y); wa0.y = pkbf(f0.z, f0.w);
            wa0.z = pkbf(f1.x, f1.y); wa0.w = pkbf(f1.z, f1.w);
            wa1.x = pkbf(f2.x, f2.y); wa1.y = pkbf(f2.z, f2.w);
            wa1.z = pkbf(f3.x, f3.y); wa1.w = pkbf(f3.z, f3.w);
        }
        if (WB) {
            const uint4* s = (const uint4*)(Wb + woff + k0);
            wb0 = s[0];
            wb1 = s[1];
        } else {
            const float4* s = (const float4*)(Wf + woff + k0);
            float4 f0 = s[0], f1 = s[1], f2 = s[2], f3 = s[3];
            wb0.x = pkbf(f0.x, f0.y); wb0.y = pkbf(f0.z, f0.w);
            wb0.z = pkbf(f1.x, f1.y); wb0.w = pkbf(f1.z, f1.w);
            wb1.x = pkbf(f2.x, f2.y); wb1.y = pkbf(f2.z, f2.w);
            wb1.z = pkbf(f3.x, f3.y); wb1.w = pkbf(f3.z, f3.w);
        }
        __syncthreads();  // previous step's readers done
        *(uint4*)&Als[row * 40 + half * 16] = wa0;
        *(uint4*)&Als[row * 40 + half * 16 + 8] = wa1;
        *(uint4*)&Bls[row * 40 + half * 16] = wb0;
        *(uint4*)&Bls[row * 40 + half * 16 + 8] = wb1;
        __syncthreads();

        short8 bf[4];
#pragma unroll
        for (int tn = 0; tn < 4; ++tn)
            bf[tn] = *(const short8*)&Bls[(wn * 64 + tn * 16 + col) * 40 + quad * 8];
#pragma unroll
        for (int tm = 0; tm < 4; ++tm) {
            short8 af = *(const short8*)&Als[(wm * 64 + tm * 16 + col) * 40 + quad * 8];
#pragma unroll
            for (int tn = 0; tn < 4; ++tn)
                acc[tm][tn] =
                    __builtin_amdgcn_mfma_f32_16x16x32_bf16(af, bf[tn], acc[tm][tn], 0, 0, 0);
        }
    }
}

// ---------- proj epilogue (shared) ----------
__device__ __forceinline__ void proj_store(f32x4 acc[4][4], unsigned short* C, float scale,
                                           int mBase, int nBase, int tid) {
    const int lane = tid & 63;
    const int wv = tid >> 6;
    const int wm = wv >> 1, wn = wv & 1;
    const int col = lane & 15;
    const int quad = lane >> 4;
#pragma unroll
    for (int tm = 0; tm < 4; ++tm) {
#pragma unroll
        for (int r = 0; r < 4; ++r) {
            const int m = mBase + wm * 64 + tm * 16 + quad * 4 + r;
            const int b = m >> 11, t = m & (T_ - 1);
#pragma unroll
            for (int tn = 0; tn < 4; ++tn) {
                const int f = nBase + wn * 64 + tn * 16 + col;
                const int h = f >> 6, d = f & 63;
                C[(((size_t)(b * H_ + h)) * T_ + t) * D_ + d] = f2bf(acc[tm][tn][r] * scale);
            }
        }
    }
}

// ---------- projections (bf16 pre-converted path) ----------
__global__ __launch_bounds__(256) void proj_b16_kernel(
    const unsigned short* __restrict__ nyb, const unsigned short* __restrict__ xb,
    const unsigned short* __restrict__ Wq1, const unsigned short* __restrict__ Wk1,
    const unsigned short* __restrict__ Wq2, const unsigned short* __restrict__ Wk2,
    const unsigned short* __restrict__ Wv, unsigned short* __restrict__ q1,
    unsigned short* __restrict__ k1, unsigned short* __restrict__ q2,
    unsigned short* __restrict__ k2, unsigned short* __restrict__ v) {
    __shared__ __align__(16) unsigned short Als[128 * 40];
    __shared__ __align__(16) unsigned short Bls[128 * 40];
    const int tid = threadIdx.x;
    const int mBase = blockIdx.y << 7, nBase = blockIdx.x << 7;

    const unsigned short* A;
    const unsigned short* W;
    unsigned short* C;
    float scale = 1.0f;
    switch (blockIdx.z) {
        case 0: A = nyb; W = Wq1; C = q1; scale = QSCALE_LOG2E; break;
        case 1: A = nyb; W = Wk1; C = k1; break;
        case 2: A = xb;  W = Wq2; C = q2; scale = QSCALE_LOG2E; break;
        case 3: A = xb;  W = Wk2; C = k2; break;
        default: A = nyb; W = Wv; C = v; break;
    }
    f32x4 acc[4][4];
#pragma unroll
    for (int i = 0; i < 4; ++i)
#pragma unroll
        for (int j = 0; j < 4; ++j) acc[i][j] = (f32x4){0.f, 0.f, 0.f, 0.f};
    mfma_gemm_body_b16(Als, Bls, A, W, mBase, nBase, tid, acc);
    proj_store(acc, C, scale, mBase, nBase, tid);
}

// ---------- projections (f32 fallback path) ----------
__global__ __launch_bounds__(256) void proj_f32_kernel(
    const float* __restrict__ noisy_y, const float* __restrict__ x,
    const float* __restrict__ Wq1, const float* __restrict__ Wk1, const float* __restrict__ Wq2,
    const float* __restrict__ Wk2, const float* __restrict__ Wv, unsigned short* __restrict__ q1,
    unsigned short* __restrict__ k1, unsigned short* __restrict__ q2,
    unsigned short* __restrict__ k2, unsigned short* __restrict__ v) {
    __shared__ __align__(16) unsigned short Als[128 * 40];
    __shared__ __align__(16) unsigned short Bls[128 * 40];
    const int tid = threadIdx.x;
    const int mBase = blockIdx.y << 7, nBase = blockIdx.x << 7;

    const float* A;
    const float* W;
    unsigned short* C;
    float scale = 1.0f;
    switch (blockIdx.z) {
        case 0: A = noisy_y; W = Wq1; C = q1; scale = QSCALE_LOG2E; break;
        case 1: A = noisy_y; W = Wk1; C = k1; break;
        case 2: A = x;       W = Wq2; C = q2; scale = QSCALE_LOG2E; break;
        case 3: A = x;       W = Wk2; C = k2; break;
        default: A = noisy_y; W = Wv; C = v; break;
    }
    f32x4 acc[4][4];
#pragma unroll
    for (int i = 0; i < 4; ++i)
#pragma unroll
        for (int j = 0; j < 4; ++j) acc[i][j] = (f32x4){0.f, 0.f, 0.f, 0.f};
    mfma_gemm_body<false, false>(Als, Bls, nullptr, A, nullptr, W, mBase, nBase, tid, acc);
    proj_store(acc, C, scale, mBase, nBase, tid);
}

// ---------- output projection (two W variants) ----------
__device__ __forceinline__ void out_store(f32x4 acc[4][4], float* out, int mBase, int nBase,
                                          int tid) {
    const int lane = tid & 63;
    const int wv = tid >> 6;
    const int wm = wv >> 1, wn = wv & 1;
    const int col = lane & 15;
    const int quad = lane >> 4;
#pragma unroll
    for (int tm = 0; tm < 4; ++tm)
#pragma unroll
        for (int r = 0; r < 4; ++r) {
            const int m = mBase + wm * 64 + tm * 16 + quad * 4 + r;
#pragma unroll
            for (int tn = 0; tn < 4; ++tn)
                out[(size_t)m * E_ + nBase + wn * 64 + tn * 16 + col] = acc[tm][tn][r];
        }
}

__global__ __launch_bounds__(256) void out_b16_kernel(const unsigned short* __restrict__ attn,
                                                      const unsigned short* __restrict__ Woutb,
                                                      float* __restrict__ out) {
    __shared__ __align__(16) unsigned short Als[128 * 40];
    __shared__ __align__(16) unsigned short Bls[128 * 40];
    const int tid = threadIdx.x;
    const int mBase = blockIdx.y << 7, nBase = blockIdx.x << 7;
    f32x4 acc[4][4];
#pragma unroll
    for (int i = 0; i < 4; ++i)
#pragma unroll
        for (int j = 0; j < 4; ++j) acc[i][j] = (f32x4){0.f, 0.f, 0.f, 0.f};
    mfma_gemm_body_b16(Als, Bls, attn, Woutb, mBase, nBase, tid, acc);
    out_store(acc, out, mBase, nBase, tid);
}

__global__ __launch_bounds__(256) void out_f32_kernel(const unsigned short* __restrict__ attn,
                                                      const float* __restrict__ Wout,
                                                      float* __restrict__ out) {
    __shared__ __align__(16) unsigned short Als[128 * 40];
    __shared__ __align__(16) unsigned short Bls[128 * 40];
    const int tid = threadIdx.x;
    const int mBase = blockIdx.y << 7, nBase = blockIdx.x << 7;
    f32x4 acc[4][4];
#pragma unroll
    for (int i = 0; i < 4; ++i)
#pragma unroll
        for (int j = 0; j < 4; ++j) acc[i][j] = (f32x4){0.f, 0.f, 0.f, 0.f};
    mfma_gemm_body<true, false>(Als, Bls, attn, nullptr, nullptr, Wout, mBase, nBase, tid, acc);
    out_store(acc, out, mBase, nBase, tid);
}

// ---------- lambda scalar ----------
__global__ void lambda_kernel(const float* __restrict__ lq1, const float* __restrict__ lk1,
                              const float* __restrict__ lq2, const float* __restrict__ lk2,
                              float* __restrict__ lam) {
    const int l = threadIdx.x;  // 64
    float s1 = lq1[l] * lk1[l];
    float s2 = lq2[l] * lk2[l];
#pragma unroll
    for (int off = 32; off; off >>= 1) {
        s1 += __shfl_xor(s1, off, 64);
        s2 += __shfl_xor(s2, off, 64);
    }
    if (l == 0) lam[0] = expf(s1) - expf(s2) + LAMBDA_INIT_F;
}

// prefetch loads for one K/V tile into NAMED scalars (round-6-proven cross-barrier
// shape: named uint4/uint2 only -- arrays/lambda-captures demote to scratch).
#define LOAD_KV(KT)                                                                        \
    {                                                                                      \
        const uint4* p1_ = (const uint4*)(k1g + base + (size_t)((KT) + kr) * D_ + dd);     \
        const uint4* p2_ = (const uint4*)(k2g + base + (size_t)((KT) + kr) * D_ + dd);     \
        k1a = p1_[0]; k1b = p1_[1]; k1c = p1_[2]; k1d = p1_[3];                            \
        k2a = p2_[0]; k2b = p2_[1]; k2c = p2_[2]; k2d = p2_[3];                            \
        const unsigned short* vp_ = vg + base + (size_t)((KT) + vR0) * D_ + vd0;           \
        vr0 = *(const uint2*)(vp_);                                                        \
        vr1 = *(const uint2*)(vp_ + D_);                                                   \
        vr2 = *(const uint2*)(vp_ + 2 * D_);                                               \
        vr3 = *(const uint2*)(vp_ + 3 * D_);                                               \
        vs0 = *(const uint2*)(vp_ + 16 * D_);                                              \
        vs1 = *(const uint2*)(vp_ + 17 * D_);                                              \
        vs2 = *(const uint2*)(vp_ + 18 * D_);                                              \
        vs3 = *(const uint2*)(vp_ + 19 * D_);                                              \
    }

// ---------- MFMA flash attention: 128 thr = 2 waves, 64 q-rows ----------
// Round-10 = round-6 (best: attn 120.5 us; 4 blocks/CU, single-buffer, named-scalar
// prefetch -- r8/r9 proved bigger blocks / dbuf regress via residency) + MERGED
// mat1/mat2 compute body. The merged body was blamed for rounds-1/2 scratch, but
// r4 proved the real cause was staging-regs-across-barriers (r3 sequential also
// scratched); merged compute was never tested with clean staging. Benefits:
// 4 independent QK MFMA chains, and V fragments read ONCE shared by both PVs
// (16 -> 8 ds_read_b128 /wave/kstep). Correctness pre-verified (r1 passed).
// Gates: WRITE_SIZE ~8.2 MB (else scratch returned -> revert to r6), VGPR <= ~170.
__global__ __launch_bounds__(128) void attn_mfma_kernel(
    const unsigned short* __restrict__ q1g, const unsigned short* __restrict__ k1g,
    const unsigned short* __restrict__ q2g, const unsigned short* __restrict__ k2g,
    const unsigned short* __restrict__ vg, const float* __restrict__ lamp,
    const float* __restrict__ subln, unsigned short* __restrict__ attn_out) {
    __shared__ __align__(16) unsigned short Ks1[64 * 72];
    __shared__ __align__(16) unsigned short Ks2[64 * 72];
    __shared__ __align__(16) unsigned short Vt[64 * 72];  // V^T: [d][virtual key]

    const int tid = threadIdx.x;
    const int lane = tid & 63;
    const int wv = tid >> 6;  // 0..1
    const int col = lane & 15;
    const int quad = lane >> 4;

    // XCD-aware remap (bijective on 1024 wgs; affects locality only, not correctness)
    const int wg = blockIdx.x + (int)blockIdx.y * (T_ / 64) + (int)blockIdx.z * (T_ / 64) * H_;
    const int xcd = wg & 7, local = wg >> 3;
    const int grp = xcd * 4 + (local >> 5);  // 0..31 = (b,h) group
    const int qt = local & 31;               // q-tile within group
    const int h = grp & (H_ - 1), b = grp >> 4;
    const size_t base = ((size_t)(b * H_ + h)) * T_ * D_;
    const int qBase = qt << 6;  // 64 q-rows per block
    const float lam = lamp[0];

    // staging geometry
    const int kr = tid >> 1;          // K row 0..63
    const int dd = (tid & 1) << 5;    // K dim half 0/32
    const int vu = tid & 7;           // V virtual-key octet
    const int vd0 = (tid >> 3) << 2;  // V dim group 0..60
    const int vR0 = 32 * (vu >> 2) + 4 * (vu & 3);  // first real key row

    // Q B-fragments for both q-sets (resident all k-steps)
    short8 Qa1[2][2], Qa2[2][2];
#pragma unroll
    for (int s = 0; s < 2; ++s) {
        const int qRow = qBase + wv * 32 + s * 16 + col;
        const unsigned short* p1 = q1g + base + (size_t)qRow * D_ + quad * 8;
        const unsigned short* p2 = q2g + base + (size_t)qRow * D_ + quad * 8;
        Qa1[s][0] = *(const short8*)p1;
        Qa1[s][1] = *(const short8*)(p1 + 32);
        Qa2[s][0] = *(const short8*)p2;
        Qa2[s][1] = *(const short8*)(p2 + 32);
    }

    f32x4 O1[2][4], O2[2][4];
#pragma unroll
    for (int s = 0; s < 2; ++s)
#pragma unroll
        for (int n = 0; n < 4; ++n) {
            O1[s][n] = (f32x4){0.f, 0.f, 0.f, 0.f};
            O2[s][n] = (f32x4){0.f, 0.f, 0.f, 0.f};
        }
    float ls1[2] = {0.f, 0.f}, ls2[2] = {0.f, 0.f};

    // named prefetch registers (cross barriers -- must stay scalars, no arrays)
    uint4 k1a, k1b, k1c, k1d, k2a, k2b, k2c, k2d;
    uint2 vr0, vr1, vr2, vr3, vs0, vs1, vs2, vs3;
    LOAD_KV(0);  // prologue prefetch

    for (int kt = 0; kt < T_; kt += 64) {
        __syncthreads();  // previous step's readers done
        {  // LDS-write phase: consume the prefetched named regs
            uint4* d1 = (uint4*)&Ks1[kr * 72 + dd];
            uint4* d2 = (uint4*)&Ks2[kr * 72 + dd];
            d1[0] = k1a; d1[1] = k1b; d1[2] = k1c; d1[3] = k1d;
            d2[0] = k2a; d2[1] = k2b; d2[2] = k2c; d2[3] = k2d;
            uint4 o;
            o.x = pklo(vr0.x, vr1.x); o.y = pklo(vr2.x, vr3.x);
            o.z = pklo(vs0.x, vs1.x); o.w = pklo(vs2.x, vs3.x);
            *(uint4*)&Vt[(vd0 + 0) * 72 + 8 * vu] = o;
            o.x = pkhi(vr0.x, vr1.x); o.y = pkhi(vr2.x, vr3.x);
            o.z = pkhi(vs0.x, vs1.x); o.w = pkhi(vs2.x, vs3.x);
            *(uint4*)&Vt[(vd0 + 1) * 72 + 8 * vu] = o;
            o.x = pklo(vr0.y, vr1.y); o.y = pklo(vr2.y, vr3.y);
            o.z = pklo(vs0.y, vs1.y); o.w = pklo(vs2.y, vs3.y);
            *(uint4*)&Vt[(vd0 + 2) * 72 + 8 * vu] = o;
            o.x = pkhi(vr0.y, vr1.y); o.y = pkhi(vr2.y, vr3.y);
            o.z = pkhi(vs0.y, vs1.y); o.w = pkhi(vs2.y, vs3.y);
            *(uint4*)&Vt[(vd0 + 3) * 72 + 8 * vu] = o;
        }
        __syncthreads();
        if (kt + 64 < T_) LOAD_KV(kt + 64);  // latency hides under compute below
        __builtin_amdgcn_s_setprio(1);

        unsigned int paU1[2][2][4], paU2[2][2][4];  // [s][chunk][word], kstep scope

        // ---- merged QK both matrices: 4 independent MFMA chains per (t,s) ----
#pragma unroll
        for (int t = 0; t < 4; ++t) {
            const int ro = (t * 16 + col) * 72 + quad * 8;
            const f32x4 z = {0.f, 0.f, 0.f, 0.f};
            short8 a0 = *(const short8*)&Ks1[ro];
            short8 a1 = *(const short8*)&Ks1[ro + 32];
            short8 b0 = *(const short8*)&Ks2[ro];
            short8 b1 = *(const short8*)&Ks2[ro + 32];
#pragma unroll
            for (int s = 0; s < 2; ++s) {
                f32x4 S1 = __builtin_amdgcn_mfma_f32_16x16x32_bf16(a0, Qa1[s][0], z, 0, 0, 0);
                S1 = __builtin_amdgcn_mfma_f32_16x16x32_bf16(a1, Qa1[s][1], S1, 0, 0, 0);
                f32x4 S2 = __builtin_amdgcn_mfma_f32_16x16x32_bf16(b0, Qa2[s][0], z, 0, 0, 0);
                S2 = __builtin_amdgcn_mfma_f32_16x16x32_bf16(b1, Qa2[s][1], S2, 0, 0, 0);
                const float p0 = fexp2(S1[0]), p1 = fexp2(S1[1]);
                const float p2 = fexp2(S1[2]), p3 = fexp2(S1[3]);
                ls1[s] += (p0 + p1) + (p2 + p3);
                paU1[s][t >> 1][(t & 1) * 2] = pkbf(p0, p1);
                paU1[s][t >> 1][(t & 1) * 2 + 1] = pkbf(p2, p3);
                const float r0 = fexp2(S2[0]), r1 = fexp2(S2[1]);
                const float r2 = fexp2(S2[2]), r3 = fexp2(S2[3]);
                ls2[s] += (r0 + r1) + (r2 + r3);
                paU2[s][t >> 1][(t & 1) * 2] = pkbf(r0, r1);
                paU2[s][t >> 1][(t & 1) * 2 + 1] = pkbf(r2, r3);
            }
        }
        // ---- merged PV: V fragment read ONCE, shared across both matrices ----
#pragma unroll
        for (int c = 0; c < 2; ++c) {
            short8 vf[4];
#pragma unroll
            for (int n = 0; n < 4; ++n)
                vf[n] = *(const short8*)&Vt[(n * 16 + col) * 72 + c * 32 + quad * 8];
#pragma unroll
            for (int s = 0; s < 2; ++s) {
                union { unsigned int u[4]; short8 s8; } pp1, pp2;
#pragma unroll
                for (int w = 0; w < 4; ++w) {
                    pp1.u[w] = paU1[s][c][w];
                    pp2.u[w] = paU2[s][c][w];
                }
#pragma unroll
                for (int n = 0; n < 4; ++n) {
                    O1[s][n] = __builtin_amdgcn_mfma_f32_16x16x32_bf16(pp1.s8, vf[n], O1[s][n],
                                                                       0, 0, 0);
                    O2[s][n] = __builtin_amdgcn_mfma_f32_16x16x32_bf16(pp2.s8, vf[n], O2[s][n],
                                                                       0, 0, 0);
                }
            }
        }
        __builtin_amdgcn_s_setprio(0);
    }

    // epilogue: per-q softmax denominators, combine, RMSNorm, affine, store bf16 [B,T,H,D]
#pragma unroll
    for (int s = 0; s < 2; ++s) {
        float s1 = ls1[s];
        s1 += __shfl_xor(s1, 16, 64);
        s1 += __shfl_xor(s1, 32, 64);
        float s2 = ls2[s];
        s2 += __shfl_xor(s2, 16, 64);
        s2 += __shfl_xor(s2, 32, 64);
        float il1[4], il2[4];
#pragma unroll
        for (int r = 0; r < 4; ++r) {
            il1[r] = 1.0f / __shfl(s1, quad * 4 + r, 64);
            il2[r] = lam / __shfl(s2, quad * 4 + r, 64);
        }
        float acc[4][4];
        float ssq[4] = {0.f, 0.f, 0.f, 0.f};
#pragma unroll
        for (int n = 0; n < 4; ++n)
#pragma unroll
            for (int r = 0; r < 4; ++r) {
                const float v = O1[s][n][r] * il1[r] - O2[s][n][r] * il2[r];
                acc[n][r] = v;
                ssq[r] += v * v;
            }
#pragma unroll
        for (int r = 0; r < 4; ++r) {
            float sv = ssq[r];
            sv += __shfl_xor(sv, 1, 64); sv += __shfl_xor(sv, 2, 64);
            sv += __shfl_xor(sv, 4, 64); sv += __shfl_xor(sv, 8, 64);
            ssq[r] = rsqrtf(sv * (1.0f / 64.0f) + EPS_) * (1.0f - LAMBDA_INIT_F);
        }
#pragma unroll
        for (int n = 0; n < 4; ++n) {
            const float sw = subln[n * 16 + col];
#pragma unroll
            for (int r = 0; r < 4; ++r) {
                const int row = qBase + wv * 32 + s * 16 + quad * 4 + r;
                attn_out[((size_t)(b * T_ + row) * H_ + h) * D_ + n * 16 + col] =
                    f2bf(acc[n][r] * ssq[r] * sw);
            }
        }
    }
}

extern "C" void kernel_launch(void* const* d_in, const int* in_sizes, int n_in, void* d_out,
                              int out_size, void* d_ws, size_t ws_size, hipStream_t stream) {
    const float* noisy_y = (const float*)d_in[0];
    const float* x = (const float*)d_in[1];
    const float* Wq1 = (const float*)d_in[2];
    const float* Wk1 = (const float*)d_in[3];
    const float* Wq2 = (const float*)d_in[4];
    const float* Wk2 = (const float*)d_in[5];
    const float* Wv = (const float*)d_in[6];
    const float* Wout = (const float*)d_in[7];
    const float* lq1 = (const float*)d_in[8];
    const float* lk1 = (const float*)d_in[9];
    const float* lq2 = (const float*)d_in[10];
    const float* lk2 = (const float*)d_in[11];
    const float* subln = (const float*)d_in[12];
    float* out = (float*)d_out;  // reference output dtype is float32

    const size_t SZ = (size_t)B_ * H_ * T_ * D_;  // 4 Mi elements
    const size_t WSZ = (size_t)E_ * E_;           // 1 Mi elements
    const size_t need = 64 + 6 * SZ * sizeof(unsigned short);                       // ~48 MiB
    const size_t need_full = need + (2 * SZ + 6 * WSZ) * sizeof(unsigned short);    // ~76 MiB
    if (ws_size < need) {
        return;  // diagnostic signature: zero output -> error 1.6797
    }
    float* lamv = (float*)d_ws;
    unsigned short* q1 = (unsigned short*)((char*)d_ws + 64);
    unsigned short* k1 = q1 + SZ;
    unsigned short* q2 = k1 + SZ;
    unsigned short* k2 = q2 + SZ;
    unsigned short* v = k2 + SZ;
    unsigned short* attn_out = v + SZ;  // [B,T,H,D] bf16

    lambda_kernel<<<1, 64, 0, stream>>>(lq1, lk1, lq2, lk2, lamv);

    if (ws_size >= need_full) {
        unsigned short* nyb = attn_out + SZ;
        unsigned short* xb = nyb + SZ;
        unsigned short* wq1b = xb + SZ;
        unsigned short* wk1b = wq1b + WSZ;
        unsigned short* wq2b = wk1b + WSZ;
        unsigned short* wk2b = wq2b + WSZ;
        unsigned short* wvb = wk2b + WSZ;
        unsigned short* woutb = wvb + WSZ;
        conv_kernel<<<dim3(1024, 8, 1), 256, 0, stream>>>(noisy_y, x, Wq1, Wk1, Wq2, Wk2, Wv,
                                                          Wout, nyb, xb, wq1b, wk1b, wq2b, wk2b,
                                                          wvb, woutb);
        proj_b16_kernel<<<dim3(E_ / 128, M_ / 128, 5), 256, 0, stream>>>(
            nyb, xb, wq1b, wk1b, wq2b, wk2b, wvb, q1, k1, q2, k2, v);
        attn_mfma_kernel<<<dim3(T_ / 64, H_, B_), 128, 0, stream>>>(q1, k1, q2, k2, v, lamv,
                                                                    subln, attn_out);
        out_b16_kernel<<<dim3(E_ / 128, M_ / 128, 1), 256, 0, stream>>>(attn_out, woutb, out);
    } else {
        proj_f32_kernel<<<dim3(E_ / 128, M_ / 128, 5), 256, 0, stream>>>(
            noisy_y, x, Wq1, Wk1, Wq2, Wk2, Wv, q1, k1, q2, k2, v);
        attn_mfma_kernel<<<dim3(T_ / 64, H_, B_), 128, 0, stream>>>(q1, k1, q2, k2, v, lamv,
                                                                    subln, attn_out);
        out_f32_kernel<<<dim3(E_ / 128, M_ / 128, 1), 256, 0, stream>>>(attn_out, Wout, out);
    }
}

// Round 12
// 214.795 us; speedup vs baseline: 1.0240x; 1.0240x over previous
//
#include <hip/hip_runtime.h>
#include <math.h>

#define B_ 2
#define T_ 2048
#define E_ 1024
#define H_ 16
#define D_ 64
#define M_ (B_ * T_)                       // 4096
#define LAMBDA_INIT_F 0.4707130183435842f  // 0.8 - 0.6*exp(-0.6)
#define EPS_ 1e-5f
#define QSCALE_LOG2E 0.18033688011112042f  // 0.125 * log2(e)

typedef __attribute__((ext_vector_type(8))) short short8;
typedef __attribute__((ext_vector_type(4))) float f32x4;

// ---------- bf16 helpers ----------
__device__ __forceinline__ unsigned short f2bf(float f) {
    union { float f; unsigned int i; } x;
    x.f = f;
    unsigned int lsb = (x.i >> 16) & 1u;
    x.i += 0x7fffu + lsb;  // round-to-nearest-even
    return (unsigned short)(x.i >> 16);
}
// pack two f32 -> two bf16 (round via +0x8000, take high halves); a=low short, b=high short
__device__ __forceinline__ unsigned int pkbf(float a, float b) {
    union { float f; unsigned int u; } x, y;
    x.f = a; y.f = b;
    return __builtin_amdgcn_perm(y.u + 0x8000u, x.u + 0x8000u, 0x07060302);
}
// pack lo16(x),lo16(y) -> one dword (x low, y high); and hi16 variant. Pure v_perm.
__device__ __forceinline__ unsigned int pklo(unsigned int x, unsigned int y) {
    return __builtin_amdgcn_perm(y, x, 0x05040100u);
}
__device__ __forceinline__ unsigned int pkhi(unsigned int x, unsigned int y) {
    return __builtin_amdgcn_perm(y, x, 0x07060302u);
}

__device__ __forceinline__ float fexp2(float x) {
#if __has_builtin(__builtin_amdgcn_exp2f)
    return __builtin_amdgcn_exp2f(x);
#else
    return exp2f(x);
#endif
}

// ---------- bulk f32 -> bf16 conversion (acts + weights), one launch ----------
__global__ __launch_bounds__(256) void conv_kernel(
    const float* __restrict__ ny, const float* __restrict__ x, const float* __restrict__ w0,
    const float* __restrict__ w1, const float* __restrict__ w2, const float* __restrict__ w3,
    const float* __restrict__ w4, const float* __restrict__ w5, unsigned short* __restrict__ nyb,
    unsigned short* __restrict__ xb, unsigned short* __restrict__ wb0,
    unsigned short* __restrict__ wb1, unsigned short* __restrict__ wb2,
    unsigned short* __restrict__ wb3, unsigned short* __restrict__ wb4,
    unsigned short* __restrict__ wb5) {
    const float* src;
    unsigned short* dst;
    int n4;
    switch (blockIdx.y) {
        case 0: src = ny; dst = nyb; n4 = (M_ * E_) / 4; break;
        case 1: src = x;  dst = xb;  n4 = (M_ * E_) / 4; break;
        case 2: src = w0; dst = wb0; n4 = (E_ * E_) / 4; break;
        case 3: src = w1; dst = wb1; n4 = (E_ * E_) / 4; break;
        case 4: src = w2; dst = wb2; n4 = (E_ * E_) / 4; break;
        case 5: src = w3; dst = wb3; n4 = (E_ * E_) / 4; break;
        case 6: src = w4; dst = wb4; n4 = (E_ * E_) / 4; break;
        default: src = w5; dst = wb5; n4 = (E_ * E_) / 4; break;
    }
    for (int i = blockIdx.x * 256 + threadIdx.x; i < n4; i += 1024 * 256) {
        float4 f = ((const float4*)src)[i];
        uint2 o;
        o.x = pkbf(f.x, f.y);
        o.y = pkbf(f.z, f.w);
        ((uint2*)dst)[i] = o;
    }
}

// ---------- MFMA GEMM core (bf16 inputs, one-step register prefetch) ----------
__device__ __forceinline__ void mfma_gemm_body_b16(unsigned short* Als, unsigned short* Bls,
                                                   const unsigned short* Ab,
                                                   const unsigned short* Wb, int mBase, int nBase,
                                                   int tid, f32x4 acc[4][4]) {
    const int lane = tid & 63;
    const int wv = tid >> 6;
    const int wm = wv >> 1, wn = wv & 1;
    const int col = lane & 15;
    const int quad = lane >> 4;
    const int row = tid >> 1;  // 0..127 staging row
    const int half = tid & 1;  // k-half: cols half*16..+16

    const size_t aoff = (size_t)(mBase + row) * E_ + half * 16;
    const size_t woff = (size_t)(nBase + row) * E_ + half * 16;

    uint4 wa0 = ((const uint4*)(Ab + aoff))[0];
    uint4 wa1 = ((const uint4*)(Ab + aoff))[1];
    uint4 wb0 = ((const uint4*)(Wb + woff))[0];
    uint4 wb1 = ((const uint4*)(Wb + woff))[1];

    for (int k0 = 0; k0 < E_; k0 += 32) {
        __syncthreads();  // previous step's readers done
        *(uint4*)&Als[row * 40 + half * 16] = wa0;
        *(uint4*)&Als[row * 40 + half * 16 + 8] = wa1;
        *(uint4*)&Bls[row * 40 + half * 16] = wb0;
        *(uint4*)&Bls[row * 40 + half * 16 + 8] = wb1;
        __syncthreads();
        if (k0 + 32 < E_) {  // prefetch next tile under this tile's compute
            wa0 = ((const uint4*)(Ab + aoff + k0 + 32))[0];
            wa1 = ((const uint4*)(Ab + aoff + k0 + 32))[1];
            wb0 = ((const uint4*)(Wb + woff + k0 + 32))[0];
            wb1 = ((const uint4*)(Wb + woff + k0 + 32))[1];
        }

        short8 bf[4];
#pragma unroll
        for (int tn = 0; tn < 4; ++tn)
            bf[tn] = *(const short8*)&Bls[(wn * 64 + tn * 16 + col) * 40 + quad * 8];
#pragma unroll
        for (int tm = 0; tm < 4; ++tm) {
            short8 af = *(const short8*)&Als[(wm * 64 + tm * 16 + col) * 40 + quad * 8];
#pragma unroll
            for (int tn = 0; tn < 4; ++tn)
                acc[tm][tn] =
                    __builtin_amdgcn_mfma_f32_16x16x32_bf16(af, bf[tn], acc[tm][tn], 0, 0, 0);
        }
    }
}

// ---------- generic GEMM core (f32 fallback paths, original structure) ----------
template <bool AB, bool WB>
__device__ __forceinline__ void mfma_gemm_body(unsigned short* Als, unsigned short* Bls,
                                               const unsigned short* Ab, const float* Af,
                                               const unsigned short* Wb, const float* Wf,
                                               int mBase, int nBase, int tid, f32x4 acc[4][4]) {
    const int lane = tid & 63;
    const int wv = tid >> 6;
    const int wm = wv >> 1, wn = wv & 1;
    const int col = lane & 15;
    const int quad = lane >> 4;
    const int row = tid >> 1;  // 0..127 staging row
    const int half = tid & 1;  // k-half: cols half*16..+16

    const size_t aoff = (size_t)(mBase + row) * E_ + half * 16;
    const size_t woff = (size_t)(nBase + row) * E_ + half * 16;

    for (int k0 = 0; k0 < E_; k0 += 32) {
        uint4 wa0, wa1, wb0, wb1;
        if (AB) {
            const uint4* s = (const uint4*)(Ab + aoff + k0);
            wa0 = s[0];
            wa1 = s[1];
        } else {
            const float4* s = (const float4*)(Af + aoff + k0);
            float4 f0 = s[0], f1 = s[1], f2 = s[2], f3 = s[3];
            wa0.x = pkbf(f0.x, f0.y); wa0.y = pkbf(f0.z, f0.w);
            wa0.z = pkbf(f1.x, f1.y); wa0.w = pkbf(f1.z, f1.w);
            wa1.x = pkbf(f2.x, f2.y); wa1.y = pkbf(f2.z, f2.w);
            wa1.z = pkbf(f3.x, f3.y); wa1.w = pkbf(f3.z, f3.w);
        }
        if (WB) {
            const uint4* s = (const uint4*)(Wb + woff + k0);
            wb0 = s[0];
            wb1 = s[1];
        } else {
            const float4* s = (const float4*)(Wf + woff + k0);
            float4 f0 = s[0], f1 = s[1], f2 = s[2], f3 = s[3];
            wb0.x = pkbf(f0.x, f0.y); wb0.y = pkbf(f0.z, f0.w);
            wb0.z = pkbf(f1.x, f1.y); wb0.w = pkbf(f1.z, f1.w);
            wb1.x = pkbf(f2.x, f2.y); wb1.y = pkbf(f2.z, f2.w);
            wb1.z = pkbf(f3.x, f3.y); wb1.w = pkbf(f3.z, f3.w);
        }
        __syncthreads();  // previous step's readers done
        *(uint4*)&Als[row * 40 + half * 16] = wa0;
        *(uint4*)&Als[row * 40 + half * 16 + 8] = wa1;
        *(uint4*)&Bls[row * 40 + half * 16] = wb0;
        *(uint4*)&Bls[row * 40 + half * 16 + 8] = wb1;
        __syncthreads();

        short8 bf[4];
#pragma unroll
        for (int tn = 0; tn < 4; ++tn)
            bf[tn] = *(const short8*)&Bls[(wn * 64 + tn * 16 + col) * 40 + quad * 8];
#pragma unroll
        for (int tm = 0; tm < 4; ++tm) {
            short8 af = *(const short8*)&Als[(wm * 64 + tm * 16 + col) * 40 + quad * 8];
#pragma unroll
            for (int tn = 0; tn < 4; ++tn)
                acc[tm][tn] =
                    __builtin_amdgcn_mfma_f32_16x16x32_bf16(af, bf[tn], acc[tm][tn], 0, 0, 0);
        }
    }
}

// ---------- proj epilogue (shared) ----------
__device__ __forceinline__ void proj_store(f32x4 acc[4][4], unsigned short* C, float scale,
                                           int mBase, int nBase, int tid) {
    const int lane = tid & 63;
    const int wv = tid >> 6;
    const int wm = wv >> 1, wn = wv & 1;
    const int col = lane & 15;
    const int quad = lane >> 4;
#pragma unroll
    for (int tm = 0; tm < 4; ++tm) {
#pragma unroll
        for (int r = 0; r < 4; ++r) {
            const int m = mBase + wm * 64 + tm * 16 + quad * 4 + r;
            const int b = m >> 11, t = m & (T_ - 1);
#pragma unroll
            for (int tn = 0; tn < 4; ++tn) {
                const int f = nBase + wn * 64 + tn * 16 + col;
                const int h = f >> 6, d = f & 63;
                C[(((size_t)(b * H_ + h)) * T_ + t) * D_ + d] = f2bf(acc[tm][tn][r] * scale);
            }
        }
    }
}

// ---------- projections (bf16 pre-converted path) ----------
__global__ __launch_bounds__(256) void proj_b16_kernel(
    const unsigned short* __restrict__ nyb, const unsigned short* __restrict__ xb,
    const unsigned short* __restrict__ Wq1, const unsigned short* __restrict__ Wk1,
    const unsigned short* __restrict__ Wq2, const unsigned short* __restrict__ Wk2,
    const unsigned short* __restrict__ Wv, unsigned short* __restrict__ q1,
    unsigned short* __restrict__ k1, unsigned short* __restrict__ q2,
    unsigned short* __restrict__ k2, unsigned short* __restrict__ v) {
    __shared__ __align__(16) unsigned short Als[128 * 40];
    __shared__ __align__(16) unsigned short Bls[128 * 40];
    const int tid = threadIdx.x;
    const int mBase = blockIdx.y << 7, nBase = blockIdx.x << 7;

    const unsigned short* A;
    const unsigned short* W;
    unsigned short* C;
    float scale = 1.0f;
    switch (blockIdx.z) {
        case 0: A = nyb; W = Wq1; C = q1; scale = QSCALE_LOG2E; break;
        case 1: A = nyb; W = Wk1; C = k1; break;
        case 2: A = xb;  W = Wq2; C = q2; scale = QSCALE_LOG2E; break;
        case 3: A = xb;  W = Wk2; C = k2; break;
        default: A = nyb; W = Wv; C = v; break;
    }
    f32x4 acc[4][4];
#pragma unroll
    for (int i = 0; i < 4; ++i)
#pragma unroll
        for (int j = 0; j < 4; ++j) acc[i][j] = (f32x4){0.f, 0.f, 0.f, 0.f};
    mfma_gemm_body_b16(Als, Bls, A, W, mBase, nBase, tid, acc);
    proj_store(acc, C, scale, mBase, nBase, tid);
}

// ---------- projections (f32 fallback path) ----------
__global__ __launch_bounds__(256) void proj_f32_kernel(
    const float* __restrict__ noisy_y, const float* __restrict__ x,
    const float* __restrict__ Wq1, const float* __restrict__ Wk1, const float* __restrict__ Wq2,
    const float* __restrict__ Wk2, const float* __restrict__ Wv, unsigned short* __restrict__ q1,
    unsigned short* __restrict__ k1, unsigned short* __restrict__ q2,
    unsigned short* __restrict__ k2, unsigned short* __restrict__ v) {
    __shared__ __align__(16) unsigned short Als[128 * 40];
    __shared__ __align__(16) unsigned short Bls[128 * 40];
    const int tid = threadIdx.x;
    const int mBase = blockIdx.y << 7, nBase = blockIdx.x << 7;

    const float* A;
    const float* W;
    unsigned short* C;
    float scale = 1.0f;
    switch (blockIdx.z) {
        case 0: A = noisy_y; W = Wq1; C = q1; scale = QSCALE_LOG2E; break;
        case 1: A = noisy_y; W = Wk1; C = k1; break;
        case 2: A = x;       W = Wq2; C = q2; scale = QSCALE_LOG2E; break;
        case 3: A = x;       W = Wk2; C = k2; break;
        default: A = noisy_y; W = Wv; C = v; break;
    }
    f32x4 acc[4][4];
#pragma unroll
    for (int i = 0; i < 4; ++i)
#pragma unroll
        for (int j = 0; j < 4; ++j) acc[i][j] = (f32x4){0.f, 0.f, 0.f, 0.f};
    mfma_gemm_body<false, false>(Als, Bls, nullptr, A, nullptr, W, mBase, nBase, tid, acc);
    proj_store(acc, C, scale, mBase, nBase, tid);
}

// ---------- output projection (two W variants) ----------
__device__ __forceinline__ void out_store(f32x4 acc[4][4], float* out, int mBase, int nBase,
                                          int tid) {
    const int lane = tid & 63;
    const int wv = tid >> 6;
    const int wm = wv >> 1, wn = wv & 1;
    const int col = lane & 15;
    const int quad = lane >> 4;
#pragma unroll
    for (int tm = 0; tm < 4; ++tm)
#pragma unroll
        for (int r = 0; r < 4; ++r) {
            const int m = mBase + wm * 64 + tm * 16 + quad * 4 + r;
#pragma unroll
            for (int tn = 0; tn < 4; ++tn)
                out[(size_t)m * E_ + nBase + wn * 64 + tn * 16 + col] = acc[tm][tn][r];
        }
}

__global__ __launch_bounds__(256) void out_b16_kernel(const unsigned short* __restrict__ attn,
                                                      const unsigned short* __restrict__ Woutb,
                                                      float* __restrict__ out) {
    __shared__ __align__(16) unsigned short Als[128 * 40];
    __shared__ __align__(16) unsigned short Bls[128 * 40];
    const int tid = threadIdx.x;
    const int mBase = blockIdx.y << 7, nBase = blockIdx.x << 7;
    f32x4 acc[4][4];
#pragma unroll
    for (int i = 0; i < 4; ++i)
#pragma unroll
        for (int j = 0; j < 4; ++j) acc[i][j] = (f32x4){0.f, 0.f, 0.f, 0.f};
    mfma_gemm_body_b16(Als, Bls, attn, Woutb, mBase, nBase, tid, acc);
    out_store(acc, out, mBase, nBase, tid);
}

__global__ __launch_bounds__(256) void out_f32_kernel(const unsigned short* __restrict__ attn,
                                                      const float* __restrict__ Wout,
                                                      float* __restrict__ out) {
    __shared__ __align__(16) unsigned short Als[128 * 40];
    __shared__ __align__(16) unsigned short Bls[128 * 40];
    const int tid = threadIdx.x;
    const int mBase = blockIdx.y << 7, nBase = blockIdx.x << 7;
    f32x4 acc[4][4];
#pragma unroll
    for (int i = 0; i < 4; ++i)
#pragma unroll
        for (int j = 0; j < 4; ++j) acc[i][j] = (f32x4){0.f, 0.f, 0.f, 0.f};
    mfma_gemm_body<true, false>(Als, Bls, attn, nullptr, nullptr, Wout, mBase, nBase, tid, acc);
    out_store(acc, out, mBase, nBase, tid);
}

// ---------- lambda scalar ----------
__global__ void lambda_kernel(const float* __restrict__ lq1, const float* __restrict__ lk1,
                              const float* __restrict__ lq2, const float* __restrict__ lk2,
                              float* __restrict__ lam) {
    const int l = threadIdx.x;  // 64
    float s1 = lq1[l] * lk1[l];
    float s2 = lq2[l] * lk2[l];
#pragma unroll
    for (int off = 32; off; off >>= 1) {
        s1 += __shfl_xor(s1, off, 64);
        s2 += __shfl_xor(s2, off, 64);
    }
    if (l == 0) lam[0] = expf(s1) - expf(s2) + LAMBDA_INIT_F;
}

// prefetch loads for one K/V tile into NAMED scalars (round-6-proven cross-barrier
// shape: named uint4/uint2 only -- arrays/lambda-captures demote to scratch).
#define LOAD_KV(KT)                                                                        \
    {                                                                                      \
        const uint4* p1_ = (const uint4*)(k1g + base + (size_t)((KT) + kr) * D_ + dd);     \
        const uint4* p2_ = (const uint4*)(k2g + base + (size_t)((KT) + kr) * D_ + dd);     \
        k1a = p1_[0]; k1b = p1_[1]; k1c = p1_[2]; k1d = p1_[3];                            \
        k2a = p2_[0]; k2b = p2_[1]; k2c = p2_[2]; k2d = p2_[3];                            \
        const unsigned short* vp_ = vg + base + (size_t)((KT) + vR0) * D_ + vd0;           \
        vr0 = *(const uint2*)(vp_);                                                        \
        vr1 = *(const uint2*)(vp_ + D_);                                                   \
        vr2 = *(const uint2*)(vp_ + 2 * D_);                                               \
        vr3 = *(const uint2*)(vp_ + 3 * D_);                                               \
        vs0 = *(const uint2*)(vp_ + 16 * D_);                                              \
        vs1 = *(const uint2*)(vp_ + 17 * D_);                                              \
        vs2 = *(const uint2*)(vp_ + 18 * D_);                                              \
        vs3 = *(const uint2*)(vp_ + 19 * D_);                                              \
    }

// ---------- MFMA flash attention: 128 thr = 2 waves, 64 q-rows ----------
// Round-11 = round-6 (best) + CHUNK-INTERLEAVED merged body + VGPR pin.
// r10 post-mortem: merged body was scratch-free but VGPR 128->156 halved
// occupancy (the active constraint is VGPR <= 128). Pipe accounting shows LDS
// datapath is the largest wall term (~46%), and V fragments are read twice
// (once per matrix). This round: per chunk c, do {QK both mats for t=2c,2c+1}
// -> {read V once} -> {PV both mats}. V reads 16 -> 8 b128/wave/kstep (-18%
// total LDS traffic), 4 independent QK chains, and peak P-liveness stays 16
// dwords == r6 (only the current chunk's pa1+pa2 live, not r10's full 32).
// __launch_bounds__(128,4) pins VGPR <= 128 (forbids the r10 failure mode;
// a forced spill instead would show in WRITE_SIZE).
// Gates: VGPR == 128, WRITE_SIZE ~8.2-9.2 MB, absmax ~9.8e-3.
__global__ __launch_bounds__(128, 4) void attn_mfma_kernel(
    const unsigned short* __restrict__ q1g, const unsigned short* __restrict__ k1g,
    const unsigned short* __restrict__ q2g, const unsigned short* __restrict__ k2g,
    const unsigned short* __restrict__ vg, const float* __restrict__ lamp,
    const float* __restrict__ subln, unsigned short* __restrict__ attn_out) {
    __shared__ __align__(16) unsigned short Ks1[64 * 72];
    __shared__ __align__(16) unsigned short Ks2[64 * 72];
    __shared__ __align__(16) unsigned short Vt[64 * 72];  // V^T: [d][virtual key]

    const int tid = threadIdx.x;
    const int lane = tid & 63;
    const int wv = tid >> 6;  // 0..1
    const int col = lane & 15;
    const int quad = lane >> 4;

    // XCD-aware remap (bijective on 1024 wgs; affects locality only, not correctness)
    const int wg = blockIdx.x + (int)blockIdx.y * (T_ / 64) + (int)blockIdx.z * (T_ / 64) * H_;
    const int xcd = wg & 7, local = wg >> 3;
    const int grp = xcd * 4 + (local >> 5);  // 0..31 = (b,h) group
    const int qt = local & 31;               // q-tile within group
    const int h = grp & (H_ - 1), b = grp >> 4;
    const size_t base = ((size_t)(b * H_ + h)) * T_ * D_;
    const int qBase = qt << 6;  // 64 q-rows per block
    const float lam = lamp[0];

    // staging geometry
    const int kr = tid >> 1;          // K row 0..63
    const int dd = (tid & 1) << 5;    // K dim half 0/32
    const int vu = tid & 7;           // V virtual-key octet
    const int vd0 = (tid >> 3) << 2;  // V dim group 0..60
    const int vR0 = 32 * (vu >> 2) + 4 * (vu & 3);  // first real key row

    // Q B-fragments for both q-sets (resident all k-steps)
    short8 Qa1[2][2], Qa2[2][2];
#pragma unroll
    for (int s = 0; s < 2; ++s) {
        const int qRow = qBase + wv * 32 + s * 16 + col;
        const unsigned short* p1 = q1g + base + (size_t)qRow * D_ + quad * 8;
        const unsigned short* p2 = q2g + base + (size_t)qRow * D_ + quad * 8;
        Qa1[s][0] = *(const short8*)p1;
        Qa1[s][1] = *(const short8*)(p1 + 32);
        Qa2[s][0] = *(const short8*)p2;
        Qa2[s][1] = *(const short8*)(p2 + 32);
    }

    f32x4 O1[2][4], O2[2][4];
#pragma unroll
    for (int s = 0; s < 2; ++s)
#pragma unroll
        for (int n = 0; n < 4; ++n) {
            O1[s][n] = (f32x4){0.f, 0.f, 0.f, 0.f};
            O2[s][n] = (f32x4){0.f, 0.f, 0.f, 0.f};
        }
    float ls1[2] = {0.f, 0.f}, ls2[2] = {0.f, 0.f};

    // named prefetch registers (cross barriers -- must stay scalars, no arrays)
    uint4 k1a, k1b, k1c, k1d, k2a, k2b, k2c, k2d;
    uint2 vr0, vr1, vr2, vr3, vs0, vs1, vs2, vs3;
    LOAD_KV(0);  // prologue prefetch

    for (int kt = 0; kt < T_; kt += 64) {
        __syncthreads();  // previous step's readers done
        {  // LDS-write phase: consume the prefetched named regs
            uint4* d1 = (uint4*)&Ks1[kr * 72 + dd];
            uint4* d2 = (uint4*)&Ks2[kr * 72 + dd];
            d1[0] = k1a; d1[1] = k1b; d1[2] = k1c; d1[3] = k1d;
            d2[0] = k2a; d2[1] = k2b; d2[2] = k2c; d2[3] = k2d;
            uint4 o;
            o.x = pklo(vr0.x, vr1.x); o.y = pklo(vr2.x, vr3.x);
            o.z = pklo(vs0.x, vs1.x); o.w = pklo(vs2.x, vs3.x);
            *(uint4*)&Vt[(vd0 + 0) * 72 + 8 * vu] = o;
            o.x = pkhi(vr0.x, vr1.x); o.y = pkhi(vr2.x, vr3.x);
            o.z = pkhi(vs0.x, vs1.x); o.w = pkhi(vs2.x, vs3.x);
            *(uint4*)&Vt[(vd0 + 1) * 72 + 8 * vu] = o;
            o.x = pklo(vr0.y, vr1.y); o.y = pklo(vr2.y, vr3.y);
            o.z = pklo(vs0.y, vs1.y); o.w = pklo(vs2.y, vs3.y);
            *(uint4*)&Vt[(vd0 + 2) * 72 + 8 * vu] = o;
            o.x = pkhi(vr0.y, vr1.y); o.y = pkhi(vr2.y, vr3.y);
            o.z = pkhi(vs0.y, vs1.y); o.w = pkhi(vs2.y, vs3.y);
            *(uint4*)&Vt[(vd0 + 3) * 72 + 8 * vu] = o;
        }
        __syncthreads();
        if (kt + 64 < T_) LOAD_KV(kt + 64);  // latency hides under compute below
        __builtin_amdgcn_s_setprio(1);

        // chunk-interleaved merged body: per chunk, QK(both mats) -> V once -> PV(both)
#pragma unroll
        for (int c = 0; c < 2; ++c) {
            unsigned int pa1[2][4], pa2[2][4];  // [s][word] -- CURRENT chunk only
#pragma unroll
            for (int tt = 0; tt < 2; ++tt) {
                const int t = c * 2 + tt;
                const int ro = (t * 16 + col) * 72 + quad * 8;
                const f32x4 z = {0.f, 0.f, 0.f, 0.f};
                short8 a0 = *(const short8*)&Ks1[ro];
                short8 a1 = *(const short8*)&Ks1[ro + 32];
                short8 b0 = *(const short8*)&Ks2[ro];
                short8 b1 = *(const short8*)&Ks2[ro + 32];
#pragma unroll
                for (int s = 0; s < 2; ++s) {
                    f32x4 S1 = __builtin_amdgcn_mfma_f32_16x16x32_bf16(a0, Qa1[s][0], z, 0, 0, 0);
                    S1 = __builtin_amdgcn_mfma_f32_16x16x32_bf16(a1, Qa1[s][1], S1, 0, 0, 0);
                    f32x4 S2 = __builtin_amdgcn_mfma_f32_16x16x32_bf16(b0, Qa2[s][0], z, 0, 0, 0);
                    S2 = __builtin_amdgcn_mfma_f32_16x16x32_bf16(b1, Qa2[s][1], S2, 0, 0, 0);
                    const float p0 = fexp2(S1[0]), p1 = fexp2(S1[1]);
                    const float p2 = fexp2(S1[2]), p3 = fexp2(S1[3]);
                    ls1[s] += (p0 + p1) + (p2 + p3);
                    pa1[s][tt * 2] = pkbf(p0, p1);
                    pa1[s][tt * 2 + 1] = pkbf(p2, p3);
                    const float r0 = fexp2(S2[0]), r1 = fexp2(S2[1]);
                    const float r2 = fexp2(S2[2]), r3 = fexp2(S2[3]);
                    ls2[s] += (r0 + r1) + (r2 + r3);
                    pa2[s][tt * 2] = pkbf(r0, r1);
                    pa2[s][tt * 2 + 1] = pkbf(r2, r3);
                }
            }
            // V fragments read ONCE for this chunk, shared by both matrices
            short8 vf[4];
#pragma unroll
            for (int n = 0; n < 4; ++n)
                vf[n] = *(const short8*)&Vt[(n * 16 + col) * 72 + c * 32 + quad * 8];
#pragma unroll
            for (int s = 0; s < 2; ++s) {
                union { unsigned int u[4]; short8 s8; } pp1, pp2;
#pragma unroll
                for (int w = 0; w < 4; ++w) {
                    pp1.u[w] = pa1[s][w];
                    pp2.u[w] = pa2[s][w];
                }
#pragma unroll
                for (int n = 0; n < 4; ++n) {
                    O1[s][n] = __builtin_amdgcn_mfma_f32_16x16x32_bf16(pp1.s8, vf[n], O1[s][n],
                                                                       0, 0, 0);
                    O2[s][n] = __builtin_amdgcn_mfma_f32_16x16x32_bf16(pp2.s8, vf[n], O2[s][n],
                                                                       0, 0, 0);
                }
            }
        }
        __builtin_amdgcn_s_setprio(0);
    }

    // epilogue: per-q softmax denominators, combine, RMSNorm, affine, store bf16 [B,T,H,D]
#pragma unroll
    for (int s = 0; s < 2; ++s) {
        float s1 = ls1[s];
        s1 += __shfl_xor(s1, 16, 64);
        s1 += __shfl_xor(s1, 32, 64);
        float s2 = ls2[s];
        s2 += __shfl_xor(s2, 16, 64);
        s2 += __shfl_xor(s2, 32, 64);
        float il1[4], il2[4];
#pragma unroll
        for (int r = 0; r < 4; ++r) {
            il1[r] = 1.0f / __shfl(s1, quad * 4 + r, 64);
            il2[r] = lam / __shfl(s2, quad * 4 + r, 64);
        }
        float acc[4][4];
        float ssq[4] = {0.f, 0.f, 0.f, 0.f};
#pragma unroll
        for (int n = 0; n < 4; ++n)
#pragma unroll
            for (int r = 0; r < 4; ++r) {
                const float v = O1[s][n][r] * il1[r] - O2[s][n][r] * il2[r];
                acc[n][r] = v;
                ssq[r] += v * v;
            }
#pragma unroll
        for (int r = 0; r < 4; ++r) {
            float sv = ssq[r];
            sv += __shfl_xor(sv, 1, 64); sv += __shfl_xor(sv, 2, 64);
            sv += __shfl_xor(sv, 4, 64); sv += __shfl_xor(sv, 8, 64);
            ssq[r] = rsqrtf(sv * (1.0f / 64.0f) + EPS_) * (1.0f - LAMBDA_INIT_F);
        }
#pragma unroll
        for (int n = 0; n < 4; ++n) {
            const float sw = subln[n * 16 + col];
#pragma unroll
            for (int r = 0; r < 4; ++r) {
                const int row = qBase + wv * 32 + s * 16 + quad * 4 + r;
                attn_out[((size_t)(b * T_ + row) * H_ + h) * D_ + n * 16 + col] =
                    f2bf(acc[n][r] * ssq[r] * sw);
            }
        }
    }
}

extern "C" void kernel_launch(void* const* d_in, const int* in_sizes, int n_in, void* d_out,
                              int out_size, void* d_ws, size_t ws_size, hipStream_t stream) {
    const float* noisy_y = (const float*)d_in[0];
    const float* x = (const float*)d_in[1];
    const float* Wq1 = (const float*)d_in[2];
    const float* Wk1 = (const float*)d_in[3];
    const float* Wq2 = (const float*)d_in[4];
    const float* Wk2 = (const float*)d_in[5];
    const float* Wv = (const float*)d_in[6];
    const float* Wout = (const float*)d_in[7];
    const float* lq1 = (const float*)d_in[8];
    const float* lk1 = (const float*)d_in[9];
    const float* lq2 = (const float*)d_in[10];
    const float* lk2 = (const float*)d_in[11];
    const float* subln = (const float*)d_in[12];
    float* out = (float*)d_out;  // reference output dtype is float32

    const size_t SZ = (size_t)B_ * H_ * T_ * D_;  // 4 Mi elements
    const size_t WSZ = (size_t)E_ * E_;           // 1 Mi elements
    const size_t need = 64 + 6 * SZ * sizeof(unsigned short);                       // ~48 MiB
    const size_t need_full = need + (2 * SZ + 6 * WSZ) * sizeof(unsigned short);    // ~76 MiB
    if (ws_size < need) {
        return;  // diagnostic signature: zero output -> error 1.6797
    }
    float* lamv = (float*)d_ws;
    unsigned short* q1 = (unsigned short*)((char*)d_ws + 64);
    unsigned short* k1 = q1 + SZ;
    unsigned short* q2 = k1 + SZ;
    unsigned short* k2 = q2 + SZ;
    unsigned short* v = k2 + SZ;
    unsigned short* attn_out = v + SZ;  // [B,T,H,D] bf16

    lambda_kernel<<<1, 64, 0, stream>>>(lq1, lk1, lq2, lk2, lamv);

    if (ws_size >= need_full) {
        unsigned short* nyb = attn_out + SZ;
        unsigned short* xb = nyb + SZ;
        unsigned short* wq1b = xb + SZ;
        unsigned short* wk1b = wq1b + WSZ;
        unsigned short* wq2b = wk1b + WSZ;
        unsigned short* wk2b = wq2b + WSZ;
        unsigned short* wvb = wk2b + WSZ;
        unsigned short* woutb = wvb + WSZ;
        conv_kernel<<<dim3(1024, 8, 1), 256, 0, stream>>>(noisy_y, x, Wq1, Wk1, Wq2, Wk2, Wv,
                                                          Wout, nyb, xb, wq1b, wk1b, wq2b, wk2b,
                                                          wvb, woutb);
        proj_b16_kernel<<<dim3(E_ / 128, M_ / 128, 5), 256, 0, stream>>>(
            nyb, xb, wq1b, wk1b, wq2b, wk2b, wvb, q1, k1, q2, k2, v);
        attn_mfma_kernel<<<dim3(T_ / 64, H_, B_), 128, 0, stream>>>(q1, k1, q2, k2, v, lamv,
                                                                    subln, attn_out);
        out_b16_kernel<<<dim3(E_ / 128, M_ / 128, 1), 256, 0, stream>>>(attn_out, woutb, out);
    } else {
        proj_f32_kernel<<<dim3(E_ / 128, M_ / 128, 5), 256, 0, stream>>>(
            noisy_y, x, Wq1, Wk1, Wq2, Wk2, Wv, q1, k1, q2, k2, v);
        attn_mfma_kernel<<<dim3(T_ / 64, H_, B_), 128, 0, stream>>>(q1, k1, q2, k2, v, lamv,
                                                                    subln, attn_out);
        out_f32_kernel<<<dim3(E_ / 128, M_ / 128, 1), 256, 0, stream>>>(attn_out, Wout, out);
    }
}

// Round 13
// 208.443 us; speedup vs baseline: 1.0552x; 1.0305x over previous
//
#include <hip/hip_runtime.h>
#include <math.h>

#define B_ 2
#define T_ 2048
#define E_ 1024
#define H_ 16
#define D_ 64
#define M_ (B_ * T_)                       // 4096
#define LAMBDA_INIT_F 0.4707130183435842f  // 0.8 - 0.6*exp(-0.6)
#define EPS_ 1e-5f
#define QSCALE_LOG2E 0.18033688011112042f  // 0.125 * log2(e)

typedef __attribute__((ext_vector_type(8))) short short8;
typedef __attribute__((ext_vector_type(4))) float f32x4;

// ---------- bf16 helpers ----------
__device__ __forceinline__ unsigned short f2bf(float f) {
    union { float f; unsigned int i; } x;
    x.f = f;
    unsigned int lsb = (x.i >> 16) & 1u;
    x.i += 0x7fffu + lsb;  // round-to-nearest-even
    return (unsigned short)(x.i >> 16);
}
// pack two f32 -> two bf16 (round via +0x8000, take high halves); a=low short, b=high short
__device__ __forceinline__ unsigned int pkbf(float a, float b) {
    union { float f; unsigned int u; } x, y;
    x.f = a; y.f = b;
    return __builtin_amdgcn_perm(y.u + 0x8000u, x.u + 0x8000u, 0x07060302);
}
// pack lo16(x),lo16(y) -> one dword (x low, y high); and hi16 variant. Pure v_perm.
__device__ __forceinline__ unsigned int pklo(unsigned int x, unsigned int y) {
    return __builtin_amdgcn_perm(y, x, 0x05040100u);
}
__device__ __forceinline__ unsigned int pkhi(unsigned int x, unsigned int y) {
    return __builtin_amdgcn_perm(y, x, 0x07060302u);
}

__device__ __forceinline__ float fexp2(float x) {
#if __has_builtin(__builtin_amdgcn_exp2f)
    return __builtin_amdgcn_exp2f(x);
#else
    return exp2f(x);
#endif
}

// ---------- bulk f32 -> bf16 conversion (acts + weights), one launch ----------
__global__ __launch_bounds__(256) void conv_kernel(
    const float* __restrict__ ny, const float* __restrict__ x, const float* __restrict__ w0,
    const float* __restrict__ w1, const float* __restrict__ w2, const float* __restrict__ w3,
    const float* __restrict__ w4, const float* __restrict__ w5, unsigned short* __restrict__ nyb,
    unsigned short* __restrict__ xb, unsigned short* __restrict__ wb0,
    unsigned short* __restrict__ wb1, unsigned short* __restrict__ wb2,
    unsigned short* __restrict__ wb3, unsigned short* __restrict__ wb4,
    unsigned short* __restrict__ wb5) {
    const float* src;
    unsigned short* dst;
    int n4;
    switch (blockIdx.y) {
        case 0: src = ny; dst = nyb; n4 = (M_ * E_) / 4; break;
        case 1: src = x;  dst = xb;  n4 = (M_ * E_) / 4; break;
        case 2: src = w0; dst = wb0; n4 = (E_ * E_) / 4; break;
        case 3: src = w1; dst = wb1; n4 = (E_ * E_) / 4; break;
        case 4: src = w2; dst = wb2; n4 = (E_ * E_) / 4; break;
        case 5: src = w3; dst = wb3; n4 = (E_ * E_) / 4; break;
        case 6: src = w4; dst = wb4; n4 = (E_ * E_) / 4; break;
        default: src = w5; dst = wb5; n4 = (E_ * E_) / 4; break;
    }
    for (int i = blockIdx.x * 256 + threadIdx.x; i < n4; i += 1024 * 256) {
        float4 f = ((const float4*)src)[i];
        uint2 o;
        o.x = pkbf(f.x, f.y);
        o.y = pkbf(f.z, f.w);
        ((uint2*)dst)[i] = o;
    }
}

// ---------- MFMA GEMM core (bf16 inputs, one-step register prefetch) ----------
// C[m,n] = sum_k A[m,k] * W[n,k]; 128x128 tile, BK=32, 256 thr = 4 waves (2x2 of 64x64).
// 16 short-lived prefetch regs/thread (measured: helped, no spill -- keep).
__device__ __forceinline__ void mfma_gemm_body_b16(unsigned short* Als, unsigned short* Bls,
                                                   const unsigned short* Ab,
                                                   const unsigned short* Wb, int mBase, int nBase,
                                                   int tid, f32x4 acc[4][4]) {
    const int lane = tid & 63;
    const int wv = tid >> 6;
    const int wm = wv >> 1, wn = wv & 1;
    const int col = lane & 15;
    const int quad = lane >> 4;
    const int row = tid >> 1;  // 0..127 staging row
    const int half = tid & 1;  // k-half: cols half*16..+16

    const size_t aoff = (size_t)(mBase + row) * E_ + half * 16;
    const size_t woff = (size_t)(nBase + row) * E_ + half * 16;

    uint4 wa0 = ((const uint4*)(Ab + aoff))[0];
    uint4 wa1 = ((const uint4*)(Ab + aoff))[1];
    uint4 wb0 = ((const uint4*)(Wb + woff))[0];
    uint4 wb1 = ((const uint4*)(Wb + woff))[1];

    for (int k0 = 0; k0 < E_; k0 += 32) {
        __syncthreads();  // previous step's readers done
        *(uint4*)&Als[row * 40 + half * 16] = wa0;
        *(uint4*)&Als[row * 40 + half * 16 + 8] = wa1;
        *(uint4*)&Bls[row * 40 + half * 16] = wb0;
        *(uint4*)&Bls[row * 40 + half * 16 + 8] = wb1;
        __syncthreads();
        if (k0 + 32 < E_) {  // prefetch next tile under this tile's compute
            wa0 = ((const uint4*)(Ab + aoff + k0 + 32))[0];
            wa1 = ((const uint4*)(Ab + aoff + k0 + 32))[1];
            wb0 = ((const uint4*)(Wb + woff + k0 + 32))[0];
            wb1 = ((const uint4*)(Wb + woff + k0 + 32))[1];
        }

        short8 bf[4];
#pragma unroll
        for (int tn = 0; tn < 4; ++tn)
            bf[tn] = *(const short8*)&Bls[(wn * 64 + tn * 16 + col) * 40 + quad * 8];
#pragma unroll
        for (int tm = 0; tm < 4; ++tm) {
            short8 af = *(const short8*)&Als[(wm * 64 + tm * 16 + col) * 40 + quad * 8];
#pragma unroll
            for (int tn = 0; tn < 4; ++tn)
                acc[tm][tn] =
                    __builtin_amdgcn_mfma_f32_16x16x32_bf16(af, bf[tn], acc[tm][tn], 0, 0, 0);
        }
    }
}

// ---------- generic GEMM core (f32 fallback paths, original structure) ----------
template <bool AB, bool WB>
__device__ __forceinline__ void mfma_gemm_body(unsigned short* Als, unsigned short* Bls,
                                               const unsigned short* Ab, const float* Af,
                                               const unsigned short* Wb, const float* Wf,
                                               int mBase, int nBase, int tid, f32x4 acc[4][4]) {
    const int lane = tid & 63;
    const int wv = tid >> 6;
    const int wm = wv >> 1, wn = wv & 1;
    const int col = lane & 15;
    const int quad = lane >> 4;
    const int row = tid >> 1;  // 0..127 staging row
    const int half = tid & 1;  // k-half: cols half*16..+16

    const size_t aoff = (size_t)(mBase + row) * E_ + half * 16;
    const size_t woff = (size_t)(nBase + row) * E_ + half * 16;

    for (int k0 = 0; k0 < E_; k0 += 32) {
        uint4 wa0, wa1, wb0, wb1;
        if (AB) {
            const uint4* s = (const uint4*)(Ab + aoff + k0);
            wa0 = s[0];
            wa1 = s[1];
        } else {
            const float4* s = (const float4*)(Af + aoff + k0);
            float4 f0 = s[0], f1 = s[1], f2 = s[2], f3 = s[3];
            wa0.x = pkbf(f0.x, f0.y); wa0.y = pkbf(f0.z, f0.w);
            wa0.z = pkbf(f1.x, f1.y); wa0.w = pkbf(f1.z, f1.w);
            wa1.x = pkbf(f2.x, f2.y); wa1.y = pkbf(f2.z, f2.w);
            wa1.z = pkbf(f3.x, f3.y); wa1.w = pkbf(f3.z, f3.w);
        }
        if (WB) {
            const uint4* s = (const uint4*)(Wb + woff + k0);
            wb0 = s[0];
            wb1 = s[1];
        } else {
            const float4* s = (const float4*)(Wf + woff + k0);
            float4 f0 = s[0], f1 = s[1], f2 = s[2], f3 = s[3];
            wb0.x = pkbf(f0.x, f0.y); wb0.y = pkbf(f0.z, f0.w);
            wb0.z = pkbf(f1.x, f1.y); wb0.w = pkbf(f1.z, f1.w);
            wb1.x = pkbf(f2.x, f2.y); wb1.y = pkbf(f2.z, f2.w);
            wb1.z = pkbf(f3.x, f3.y); wb1.w = pkbf(f3.z, f3.w);
        }
        __syncthreads();  // previous step's readers done
        *(uint4*)&Als[row * 40 + half * 16] = wa0;
        *(uint4*)&Als[row * 40 + half * 16 + 8] = wa1;
        *(uint4*)&Bls[row * 40 + half * 16] = wb0;
        *(uint4*)&Bls[row * 40 + half * 16 + 8] = wb1;
        __syncthreads();

        short8 bf[4];
#pragma unroll
        for (int tn = 0; tn < 4; ++tn)
            bf[tn] = *(const short8*)&Bls[(wn * 64 + tn * 16 + col) * 40 + quad * 8];
#pragma unroll
        for (int tm = 0; tm < 4; ++tm) {
            short8 af = *(const short8*)&Als[(wm * 64 + tm * 16 + col) * 40 + quad * 8];
#pragma unroll
            for (int tn = 0; tn < 4; ++tn)
                acc[tm][tn] =
                    __builtin_amdgcn_mfma_f32_16x16x32_bf16(af, bf[tn], acc[tm][tn], 0, 0, 0);
        }
    }
}

// ---------- proj epilogue (shared) ----------
__device__ __forceinline__ void proj_store(f32x4 acc[4][4], unsigned short* C, float scale,
                                           int mBase, int nBase, int tid) {
    const int lane = tid & 63;
    const int wv = tid >> 6;
    const int wm = wv >> 1, wn = wv & 1;
    const int col = lane & 15;
    const int quad = lane >> 4;
#pragma unroll
    for (int tm = 0; tm < 4; ++tm) {
#pragma unroll
        for (int r = 0; r < 4; ++r) {
            const int m = mBase + wm * 64 + tm * 16 + quad * 4 + r;
            const int b = m >> 11, t = m & (T_ - 1);
#pragma unroll
            for (int tn = 0; tn < 4; ++tn) {
                const int f = nBase + wn * 64 + tn * 16 + col;
                const int h = f >> 6, d = f & 63;
                C[(((size_t)(b * H_ + h)) * T_ + t) * D_ + d] = f2bf(acc[tm][tn][r] * scale);
            }
        }
    }
}

// ---------- projections (bf16 pre-converted path) ----------
__global__ __launch_bounds__(256) void proj_b16_kernel(
    const unsigned short* __restrict__ nyb, const unsigned short* __restrict__ xb,
    const unsigned short* __restrict__ Wq1, const unsigned short* __restrict__ Wk1,
    const unsigned short* __restrict__ Wq2, const unsigned short* __restrict__ Wk2,
    const unsigned short* __restrict__ Wv, unsigned short* __restrict__ q1,
    unsigned short* __restrict__ k1, unsigned short* __restrict__ q2,
    unsigned short* __restrict__ k2, unsigned short* __restrict__ v) {
    __shared__ __align__(16) unsigned short Als[128 * 40];
    __shared__ __align__(16) unsigned short Bls[128 * 40];
    const int tid = threadIdx.x;
    const int mBase = blockIdx.y << 7, nBase = blockIdx.x << 7;

    const unsigned short* A;
    const unsigned short* W;
    unsigned short* C;
    float scale = 1.0f;
    switch (blockIdx.z) {
        case 0: A = nyb; W = Wq1; C = q1; scale = QSCALE_LOG2E; break;
        case 1: A = nyb; W = Wk1; C = k1; break;
        case 2: A = xb;  W = Wq2; C = q2; scale = QSCALE_LOG2E; break;
        case 3: A = xb;  W = Wk2; C = k2; break;
        default: A = nyb; W = Wv; C = v; break;
    }
    f32x4 acc[4][4];
#pragma unroll
    for (int i = 0; i < 4; ++i)
#pragma unroll
        for (int j = 0; j < 4; ++j) acc[i][j] = (f32x4){0.f, 0.f, 0.f, 0.f};
    mfma_gemm_body_b16(Als, Bls, A, W, mBase, nBase, tid, acc);
    proj_store(acc, C, scale, mBase, nBase, tid);
}

// ---------- projections (f32 fallback path) ----------
__global__ __launch_bounds__(256) void proj_f32_kernel(
    const float* __restrict__ noisy_y, const float* __restrict__ x,
    const float* __restrict__ Wq1, const float* __restrict__ Wk1, const float* __restrict__ Wq2,
    const float* __restrict__ Wk2, const float* __restrict__ Wv, unsigned short* __restrict__ q1,
    unsigned short* __restrict__ k1, unsigned short* __restrict__ q2,
    unsigned short* __restrict__ k2, unsigned short* __restrict__ v) {
    __shared__ __align__(16) unsigned short Als[128 * 40];
    __shared__ __align__(16) unsigned short Bls[128 * 40];
    const int tid = threadIdx.x;
    const int mBase = blockIdx.y << 7, nBase = blockIdx.x << 7;

    const float* A;
    const float* W;
    unsigned short* C;
    float scale = 1.0f;
    switch (blockIdx.z) {
        case 0: A = noisy_y; W = Wq1; C = q1; scale = QSCALE_LOG2E; break;
        case 1: A = noisy_y; W = Wk1; C = k1; break;
        case 2: A = x;       W = Wq2; C = q2; scale = QSCALE_LOG2E; break;
        case 3: A = x;       W = Wk2; C = k2; break;
        default: A = noisy_y; W = Wv; C = v; break;
    }
    f32x4 acc[4][4];
#pragma unroll
    for (int i = 0; i < 4; ++i)
#pragma unroll
        for (int j = 0; j < 4; ++j) acc[i][j] = (f32x4){0.f, 0.f, 0.f, 0.f};
    mfma_gemm_body<false, false>(Als, Bls, nullptr, A, nullptr, W, mBase, nBase, tid, acc);
    proj_store(acc, C, scale, mBase, nBase, tid);
}

// ---------- output projection (two W variants) ----------
__device__ __forceinline__ void out_store(f32x4 acc[4][4], float* out, int mBase, int nBase,
                                          int tid) {
    const int lane = tid & 63;
    const int wv = tid >> 6;
    const int wm = wv >> 1, wn = wv & 1;
    const int col = lane & 15;
    const int quad = lane >> 4;
#pragma unroll
    for (int tm = 0; tm < 4; ++tm)
#pragma unroll
        for (int r = 0; r < 4; ++r) {
            const int m = mBase + wm * 64 + tm * 16 + quad * 4 + r;
#pragma unroll
            for (int tn = 0; tn < 4; ++tn)
                out[(size_t)m * E_ + nBase + wn * 64 + tn * 16 + col] = acc[tm][tn][r];
        }
}

__global__ __launch_bounds__(256) void out_b16_kernel(const unsigned short* __restrict__ attn,
                                                      const unsigned short* __restrict__ Woutb,
                                                      float* __restrict__ out) {
    __shared__ __align__(16) unsigned short Als[128 * 40];
    __shared__ __align__(16) unsigned short Bls[128 * 40];
    const int tid = threadIdx.x;
    const int mBase = blockIdx.y << 7, nBase = blockIdx.x << 7;
    f32x4 acc[4][4];
#pragma unroll
    for (int i = 0; i < 4; ++i)
#pragma unroll
        for (int j = 0; j < 4; ++j) acc[i][j] = (f32x4){0.f, 0.f, 0.f, 0.f};
    mfma_gemm_body_b16(Als, Bls, attn, Woutb, mBase, nBase, tid, acc);
    out_store(acc, out, mBase, nBase, tid);
}

__global__ __launch_bounds__(256) void out_f32_kernel(const unsigned short* __restrict__ attn,
                                                      const float* __restrict__ Wout,
                                                      float* __restrict__ out) {
    __shared__ __align__(16) unsigned short Als[128 * 40];
    __shared__ __align__(16) unsigned short Bls[128 * 40];
    const int tid = threadIdx.x;
    const int mBase = blockIdx.y << 7, nBase = blockIdx.x << 7;
    f32x4 acc[4][4];
#pragma unroll
    for (int i = 0; i < 4; ++i)
#pragma unroll
        for (int j = 0; j < 4; ++j) acc[i][j] = (f32x4){0.f, 0.f, 0.f, 0.f};
    mfma_gemm_body<true, false>(Als, Bls, attn, nullptr, nullptr, Wout, mBase, nBase, tid, acc);
    out_store(acc, out, mBase, nBase, tid);
}

// ---------- lambda scalar ----------
__global__ void lambda_kernel(const float* __restrict__ lq1, const float* __restrict__ lk1,
                              const float* __restrict__ lq2, const float* __restrict__ lk2,
                              float* __restrict__ lam) {
    const int l = threadIdx.x;  // 64
    float s1 = lq1[l] * lk1[l];
    float s2 = lq2[l] * lk2[l];
#pragma unroll
    for (int off = 32; off; off >>= 1) {
        s1 += __shfl_xor(s1, off, 64);
        s2 += __shfl_xor(s2, off, 64);
    }
    if (l == 0) lam[0] = expf(s1) - expf(s2) + LAMBDA_INIT_F;
}

// prefetch loads for one K/V tile into NAMED scalars (GEMM-proven cross-barrier
// shape: named uint4/uint2 only -- arrays/lambda-captures demote to scratch).
#define LOAD_KV(KT)                                                                        \
    {                                                                                      \
        const uint4* p1_ = (const uint4*)(k1g + base + (size_t)((KT) + kr) * D_ + dd);     \
        const uint4* p2_ = (const uint4*)(k2g + base + (size_t)((KT) + kr) * D_ + dd);     \
        k1a = p1_[0]; k1b = p1_[1]; k1c = p1_[2]; k1d = p1_[3];                            \
        k2a = p2_[0]; k2b = p2_[1]; k2c = p2_[2]; k2d = p2_[3];                            \
        const unsigned short* vp_ = vg + base + (size_t)((KT) + vR0) * D_ + vd0;           \
        vr0 = *(const uint2*)(vp_);                                                        \
        vr1 = *(const uint2*)(vp_ + D_);                                                   \
        vr2 = *(const uint2*)(vp_ + 2 * D_);                                               \
        vr3 = *(const uint2*)(vp_ + 3 * D_);                                               \
        vs0 = *(const uint2*)(vp_ + 16 * D_);                                              \
        vs1 = *(const uint2*)(vp_ + 17 * D_);                                              \
        vs2 = *(const uint2*)(vp_ + 18 * D_);                                              \
        vs3 = *(const uint2*)(vp_ + 19 * D_);                                              \
    }

// ---------- MFMA flash attention: 128 thr = 2 waves, 64 q-rows ----------
// FINAL (= round-6, the measured optimum: attn 120.5 us, total 208.7 us).
// Structure: single-buffered K1/K2/Vt LDS staging; GEMM-style one-step register
// prefetch (barrier -> LDS-write of prev named regs -> barrier -> load next tile
// into NAMED scalars -> compute) -- the only cross-barrier staging shape that
// stays scratch-free (r1-r4 forensics); virtual-key-order Vt (PV B-fragment =
// one even-banked ds_read_b128); XCD remap (KV L2-resident, FETCH 107->20.5 MB);
// sequential mat1->mat2 with kstep-scope paU; setprio over compute.
// Probed and rejected: K-from-global (r5 -40%), 4x1-qset waves (r7/r8 null),
// dbuf/128-row blocks (r9 -14%), merged bodies (r10/r11 -13..16%: VGPR >128
// halves occupancy -- the active constraint is the VGPR=128 <-> 4 blocks/CU edge).
__global__ __launch_bounds__(128) void attn_mfma_kernel(
    const unsigned short* __restrict__ q1g, const unsigned short* __restrict__ k1g,
    const unsigned short* __restrict__ q2g, const unsigned short* __restrict__ k2g,
    const unsigned short* __restrict__ vg, const float* __restrict__ lamp,
    const float* __restrict__ subln, unsigned short* __restrict__ attn_out) {
    __shared__ __align__(16) unsigned short Ks1[64 * 72];
    __shared__ __align__(16) unsigned short Ks2[64 * 72];
    __shared__ __align__(16) unsigned short Vt[64 * 72];  // V^T: [d][virtual key]

    const int tid = threadIdx.x;
    const int lane = tid & 63;
    const int wv = tid >> 6;  // 0..1
    const int col = lane & 15;
    const int quad = lane >> 4;

    // XCD-aware remap (bijective on 1024 wgs; affects locality only, not correctness)
    const int wg = blockIdx.x + (int)blockIdx.y * (T_ / 64) + (int)blockIdx.z * (T_ / 64) * H_;
    const int xcd = wg & 7, local = wg >> 3;
    const int grp = xcd * 4 + (local >> 5);  // 0..31 = (b,h) group
    const int qt = local & 31;               // q-tile within group
    const int h = grp & (H_ - 1), b = grp >> 4;
    const size_t base = ((size_t)(b * H_ + h)) * T_ * D_;
    const int qBase = qt << 6;  // 64 q-rows per block
    const float lam = lamp[0];

    // staging geometry
    const int kr = tid >> 1;          // K row 0..63
    const int dd = (tid & 1) << 5;    // K dim half 0/32
    const int vu = tid & 7;           // V virtual-key octet
    const int vd0 = (tid >> 3) << 2;  // V dim group 0..60
    const int vR0 = 32 * (vu >> 2) + 4 * (vu & 3);  // first real key row

    // Q B-fragments for both q-sets (resident all k-steps)
    short8 Qa1[2][2], Qa2[2][2];
#pragma unroll
    for (int s = 0; s < 2; ++s) {
        const int qRow = qBase + wv * 32 + s * 16 + col;
        const unsigned short* p1 = q1g + base + (size_t)qRow * D_ + quad * 8;
        const unsigned short* p2 = q2g + base + (size_t)qRow * D_ + quad * 8;
        Qa1[s][0] = *(const short8*)p1;
        Qa1[s][1] = *(const short8*)(p1 + 32);
        Qa2[s][0] = *(const short8*)p2;
        Qa2[s][1] = *(const short8*)(p2 + 32);
    }

    f32x4 O1[2][4], O2[2][4];
#pragma unroll
    for (int s = 0; s < 2; ++s)
#pragma unroll
        for (int n = 0; n < 4; ++n) {
            O1[s][n] = (f32x4){0.f, 0.f, 0.f, 0.f};
            O2[s][n] = (f32x4){0.f, 0.f, 0.f, 0.f};
        }
    float ls1[2] = {0.f, 0.f}, ls2[2] = {0.f, 0.f};

    // named prefetch registers (cross barriers -- must stay scalars, no arrays)
    uint4 k1a, k1b, k1c, k1d, k2a, k2b, k2c, k2d;
    uint2 vr0, vr1, vr2, vr3, vs0, vs1, vs2, vs3;
    LOAD_KV(0);  // prologue prefetch

    for (int kt = 0; kt < T_; kt += 64) {
        __syncthreads();  // previous step's readers done
        {  // LDS-write phase: consume the prefetched named regs
            uint4* d1 = (uint4*)&Ks1[kr * 72 + dd];
            uint4* d2 = (uint4*)&Ks2[kr * 72 + dd];
            d1[0] = k1a; d1[1] = k1b; d1[2] = k1c; d1[3] = k1d;
            d2[0] = k2a; d2[1] = k2b; d2[2] = k2c; d2[3] = k2d;
            uint4 o;
            o.x = pklo(vr0.x, vr1.x); o.y = pklo(vr2.x, vr3.x);
            o.z = pklo(vs0.x, vs1.x); o.w = pklo(vs2.x, vs3.x);
            *(uint4*)&Vt[(vd0 + 0) * 72 + 8 * vu] = o;
            o.x = pkhi(vr0.x, vr1.x); o.y = pkhi(vr2.x, vr3.x);
            o.z = pkhi(vs0.x, vs1.x); o.w = pkhi(vs2.x, vs3.x);
            *(uint4*)&Vt[(vd0 + 1) * 72 + 8 * vu] = o;
            o.x = pklo(vr0.y, vr1.y); o.y = pklo(vr2.y, vr3.y);
            o.z = pklo(vs0.y, vs1.y); o.w = pklo(vs2.y, vs3.y);
            *(uint4*)&Vt[(vd0 + 2) * 72 + 8 * vu] = o;
            o.x = pkhi(vr0.y, vr1.y); o.y = pkhi(vr2.y, vr3.y);
            o.z = pkhi(vs0.y, vs1.y); o.w = pkhi(vs2.y, vs3.y);
            *(uint4*)&Vt[(vd0 + 3) * 72 + 8 * vu] = o;
        }
        __syncthreads();
        if (kt + 64 < T_) LOAD_KV(kt + 64);  // latency hides under compute below
        __builtin_amdgcn_s_setprio(1);

        unsigned int paU[2][2][4];  // [s][chunk][word], kstep scope, shared mat1/mat2

        {  // ---- matrix 1: QK -> exp2 -> in-register P -> PV ----
#pragma unroll
            for (int t = 0; t < 4; ++t) {
                const int ro = (t * 16 + col) * 72 + quad * 8;
                const f32x4 z = {0.f, 0.f, 0.f, 0.f};
                short8 a0 = *(const short8*)&Ks1[ro];
                short8 a1 = *(const short8*)&Ks1[ro + 32];
#pragma unroll
                for (int s = 0; s < 2; ++s) {
                    f32x4 S = __builtin_amdgcn_mfma_f32_16x16x32_bf16(a0, Qa1[s][0], z, 0, 0, 0);
                    S = __builtin_amdgcn_mfma_f32_16x16x32_bf16(a1, Qa1[s][1], S, 0, 0, 0);
                    const float p0 = fexp2(S[0]), p1 = fexp2(S[1]);
                    const float p2 = fexp2(S[2]), p3 = fexp2(S[3]);
                    ls1[s] += (p0 + p1) + (p2 + p3);
                    paU[s][t >> 1][(t & 1) * 2] = pkbf(p0, p1);
                    paU[s][t >> 1][(t & 1) * 2 + 1] = pkbf(p2, p3);
                }
            }
#pragma unroll
            for (int c = 0; c < 2; ++c) {
                short8 vf[4];
#pragma unroll
                for (int n = 0; n < 4; ++n)
                    vf[n] = *(const short8*)&Vt[(n * 16 + col) * 72 + c * 32 + quad * 8];
#pragma unroll
                for (int s = 0; s < 2; ++s) {
                    union { unsigned int u[4]; short8 s8; } pp;
#pragma unroll
                    for (int w = 0; w < 4; ++w) pp.u[w] = paU[s][c][w];
#pragma unroll
                    for (int n = 0; n < 4; ++n)
                        O1[s][n] = __builtin_amdgcn_mfma_f32_16x16x32_bf16(pp.s8, vf[n],
                                                                           O1[s][n], 0, 0, 0);
                }
            }
        }
        {  // ---- matrix 2 ----
#pragma unroll
            for (int t = 0; t < 4; ++t) {
                const int ro = (t * 16 + col) * 72 + quad * 8;
                const f32x4 z = {0.f, 0.f, 0.f, 0.f};
                short8 a0 = *(const short8*)&Ks2[ro];
                short8 a1 = *(const short8*)&Ks2[ro + 32];
#pragma unroll
                for (int s = 0; s < 2; ++s) {
                    f32x4 S = __builtin_amdgcn_mfma_f32_16x16x32_bf16(a0, Qa2[s][0], z, 0, 0, 0);
                    S = __builtin_amdgcn_mfma_f32_16x16x32_bf16(a1, Qa2[s][1], S, 0, 0, 0);
                    const float p0 = fexp2(S[0]), p1 = fexp2(S[1]);
                    const float p2 = fexp2(S[2]), p3 = fexp2(S[3]);
                    ls2[s] += (p0 + p1) + (p2 + p3);
                    paU[s][t >> 1][(t & 1) * 2] = pkbf(p0, p1);
                    paU[s][t >> 1][(t & 1) * 2 + 1] = pkbf(p2, p3);
                }
            }
#pragma unroll
            for (int c = 0; c < 2; ++c) {
                short8 vf[4];
#pragma unroll
                for (int n = 0; n < 4; ++n)
                    vf[n] = *(const short8*)&Vt[(n * 16 + col) * 72 + c * 32 + quad * 8];
#pragma unroll
                for (int s = 0; s < 2; ++s) {
                    union { unsigned int u[4]; short8 s8; } pp;
#pragma unroll
                    for (int w = 0; w < 4; ++w) pp.u[w] = paU[s][c][w];
#pragma unroll
                    for (int n = 0; n < 4; ++n)
                        O2[s][n] = __builtin_amdgcn_mfma_f32_16x16x32_bf16(pp.s8, vf[n],
                                                                           O2[s][n], 0, 0, 0);
                }
            }
        }
        __builtin_amdgcn_s_setprio(0);
    }

    // epilogue: per-q softmax denominators, combine, RMSNorm, affine, store bf16 [B,T,H,D]
#pragma unroll
    for (int s = 0; s < 2; ++s) {
        float s1 = ls1[s];
        s1 += __shfl_xor(s1, 16, 64);
        s1 += __shfl_xor(s1, 32, 64);
        float s2 = ls2[s];
        s2 += __shfl_xor(s2, 16, 64);
        s2 += __shfl_xor(s2, 32, 64);
        float il1[4], il2[4];
#pragma unroll
        for (int r = 0; r < 4; ++r) {
            il1[r] = 1.0f / __shfl(s1, quad * 4 + r, 64);
            il2[r] = lam / __shfl(s2, quad * 4 + r, 64);
        }
        float acc[4][4];
        float ssq[4] = {0.f, 0.f, 0.f, 0.f};
#pragma unroll
        for (int n = 0; n < 4; ++n)
#pragma unroll
            for (int r = 0; r < 4; ++r) {
                const float v = O1[s][n][r] * il1[r] - O2[s][n][r] * il2[r];
                acc[n][r] = v;
                ssq[r] += v * v;
            }
#pragma unroll
        for (int r = 0; r < 4; ++r) {
            float sv = ssq[r];
            sv += __shfl_xor(sv, 1, 64); sv += __shfl_xor(sv, 2, 64);
            sv += __shfl_xor(sv, 4, 64); sv += __shfl_xor(sv, 8, 64);
            ssq[r] = rsqrtf(sv * (1.0f / 64.0f) + EPS_) * (1.0f - LAMBDA_INIT_F);
        }
#pragma unroll
        for (int n = 0; n < 4; ++n) {
            const float sw = subln[n * 16 + col];
#pragma unroll
            for (int r = 0; r < 4; ++r) {
                const int row = qBase + wv * 32 + s * 16 + quad * 4 + r;
                attn_out[((size_t)(b * T_ + row) * H_ + h) * D_ + n * 16 + col] =
                    f2bf(acc[n][r] * ssq[r] * sw);
            }
        }
    }
}

extern "C" void kernel_launch(void* const* d_in, const int* in_sizes, int n_in, void* d_out,
                              int out_size, void* d_ws, size_t ws_size, hipStream_t stream) {
    const float* noisy_y = (const float*)d_in[0];
    const float* x = (const float*)d_in[1];
    const float* Wq1 = (const float*)d_in[2];
    const float* Wk1 = (const float*)d_in[3];
    const float* Wq2 = (const float*)d_in[4];
    const float* Wk2 = (const float*)d_in[5];
    const float* Wv = (const float*)d_in[6];
    const float* Wout = (const float*)d_in[7];
    const float* lq1 = (const float*)d_in[8];
    const float* lk1 = (const float*)d_in[9];
    const float* lq2 = (const float*)d_in[10];
    const float* lk2 = (const float*)d_in[11];
    const float* subln = (const float*)d_in[12];
    float* out = (float*)d_out;  // reference output dtype is float32

    const size_t SZ = (size_t)B_ * H_ * T_ * D_;  // 4 Mi elements
    const size_t WSZ = (size_t)E_ * E_;           // 1 Mi elements
    const size_t need = 64 + 6 * SZ * sizeof(unsigned short);                       // ~48 MiB
    const size_t need_full = need + (2 * SZ + 6 * WSZ) * sizeof(unsigned short);    // ~76 MiB
    if (ws_size < need) {
        return;  // diagnostic signature: zero output -> error 1.6797
    }
    float* lamv = (float*)d_ws;
    unsigned short* q1 = (unsigned short*)((char*)d_ws + 64);
    unsigned short* k1 = q1 + SZ;
    unsigned short* q2 = k1 + SZ;
    unsigned short* k2 = q2 + SZ;
    unsigned short* v = k2 + SZ;
    unsigned short* attn_out = v + SZ;  // [B,T,H,D] bf16

    lambda_kernel<<<1, 64, 0, stream>>>(lq1, lk1, lq2, lk2, lamv);

    if (ws_size >= need_full) {
        unsigned short* nyb = attn_out + SZ;
        unsigned short* xb = nyb + SZ;
        unsigned short* wq1b = xb + SZ;
        unsigned short* wk1b = wq1b + WSZ;
        unsigned short* wq2b = wk1b + WSZ;
        unsigned short* wk2b = wq2b + WSZ;
        unsigned short* wvb = wk2b + WSZ;
        unsigned short* woutb = wvb + WSZ;
        conv_kernel<<<dim3(1024, 8, 1), 256, 0, stream>>>(noisy_y, x, Wq1, Wk1, Wq2, Wk2, Wv,
                                                          Wout, nyb, xb, wq1b, wk1b, wq2b, wk2b,
                                                          wvb, woutb);
        proj_b16_kernel<<<dim3(E_ / 128, M_ / 128, 5), 256, 0, stream>>>(
            nyb, xb, wq1b, wk1b, wq2b, wk2b, wvb, q1, k1, q2, k2, v);
        attn_mfma_kernel<<<dim3(T_ / 64, H_, B_), 128, 0, stream>>>(q1, k1, q2, k2, v, lamv,
                                                                    subln, attn_out);
        out_b16_kernel<<<dim3(E_ / 128, M_ / 128, 1), 256, 0, stream>>>(attn_out, woutb, out);
    } else {
        proj_f32_kernel<<<dim3(E_ / 128, M_ / 128, 5), 256, 0, stream>>>(
            noisy_y, x, Wq1, Wk1, Wq2, Wk2, Wv, q1, k1, q2, k2, v);
        attn_mfma_kernel<<<dim3(T_ / 64, H_, B_), 128, 0, stream>>>(q1, k1, q2, k2, v, lamv,
                                                                    subln, attn_out);
        out_f32_kernel<<<dim3(E_ / 128, M_ / 128, 1), 256, 0, stream>>>(attn_out, Wout, out);
    }
}

// Round 14
// 207.405 us; speedup vs baseline: 1.0604x; 1.0050x over previous
//
#include <hip/hip_runtime.h>
#include <math.h>

#define B_ 2
#define T_ 2048
#define E_ 1024
#define H_ 16
#define D_ 64
#define M_ (B_ * T_)                       // 4096
#define LAMBDA_INIT_F 0.4707130183435842f  // 0.8 - 0.6*exp(-0.6)
#define EPS_ 1e-5f
#define QSCALE_LOG2E 0.18033688011112042f  // 0.125 * log2(e)

typedef __attribute__((ext_vector_type(8))) short short8;
typedef __attribute__((ext_vector_type(4))) float f32x4;

// ---------- bf16 helpers ----------
__device__ __forceinline__ unsigned short f2bf(float f) {
    union { float f; unsigned int i; } x;
    x.f = f;
    unsigned int lsb = (x.i >> 16) & 1u;
    x.i += 0x7fffu + lsb;  // round-to-nearest-even
    return (unsigned short)(x.i >> 16);
}
// pack two f32 -> two bf16 (round via +0x8000, take high halves); a=low short, b=high short
__device__ __forceinline__ unsigned int pkbf(float a, float b) {
    union { float f; unsigned int u; } x, y;
    x.f = a; y.f = b;
    return __builtin_amdgcn_perm(y.u + 0x8000u, x.u + 0x8000u, 0x07060302);
}
// single-instruction packed convert (gfx950 has no builtin; T12 recipe).
// dst.lo16 = bf16(a), dst.hi16 = bf16(b) -- replaces pkbf's 3 VALU ops with 1.
__device__ __forceinline__ unsigned int cvtpk(float a, float b) {
    unsigned int r;
    asm("v_cvt_pk_bf16_f32 %0, %1, %2" : "=v"(r) : "v"(a), "v"(b));
    return r;
}
// pack lo16(x),lo16(y) -> one dword (x low, y high); and hi16 variant. Pure v_perm.
__device__ __forceinline__ unsigned int pklo(unsigned int x, unsigned int y) {
    return __builtin_amdgcn_perm(y, x, 0x05040100u);
}
__device__ __forceinline__ unsigned int pkhi(unsigned int x, unsigned int y) {
    return __builtin_amdgcn_perm(y, x, 0x07060302u);
}

__device__ __forceinline__ float fexp2(float x) {
#if __has_builtin(__builtin_amdgcn_exp2f)
    return __builtin_amdgcn_exp2f(x);
#else
    return exp2f(x);
#endif
}

// ---------- bulk f32 -> bf16 conversion (acts + weights), one launch ----------
__global__ __launch_bounds__(256) void conv_kernel(
    const float* __restrict__ ny, const float* __restrict__ x, const float* __restrict__ w0,
    const float* __restrict__ w1, const float* __restrict__ w2, const float* __restrict__ w3,
    const float* __restrict__ w4, const float* __restrict__ w5, unsigned short* __restrict__ nyb,
    unsigned short* __restrict__ xb, unsigned short* __restrict__ wb0,
    unsigned short* __restrict__ wb1, unsigned short* __restrict__ wb2,
    unsigned short* __restrict__ wb3, unsigned short* __restrict__ wb4,
    unsigned short* __restrict__ wb5) {
    const float* src;
    unsigned short* dst;
    int n4;
    switch (blockIdx.y) {
        case 0: src = ny; dst = nyb; n4 = (M_ * E_) / 4; break;
        case 1: src = x;  dst = xb;  n4 = (M_ * E_) / 4; break;
        case 2: src = w0; dst = wb0; n4 = (E_ * E_) / 4; break;
        case 3: src = w1; dst = wb1; n4 = (E_ * E_) / 4; break;
        case 4: src = w2; dst = wb2; n4 = (E_ * E_) / 4; break;
        case 5: src = w3; dst = wb3; n4 = (E_ * E_) / 4; break;
        case 6: src = w4; dst = wb4; n4 = (E_ * E_) / 4; break;
        default: src = w5; dst = wb5; n4 = (E_ * E_) / 4; break;
    }
    for (int i = blockIdx.x * 256 + threadIdx.x; i < n4; i += 1024 * 256) {
        float4 f = ((const float4*)src)[i];
        uint2 o;
        o.x = pkbf(f.x, f.y);
        o.y = pkbf(f.z, f.w);
        ((uint2*)dst)[i] = o;
    }
}

// ---------- MFMA GEMM core (bf16 inputs, one-step register prefetch) ----------
// C[m,n] = sum_k A[m,k] * W[n,k]; 128x128 tile, BK=32, 256 thr = 4 waves (2x2 of 64x64).
__device__ __forceinline__ void mfma_gemm_body_b16(unsigned short* Als, unsigned short* Bls,
                                                   const unsigned short* Ab,
                                                   const unsigned short* Wb, int mBase, int nBase,
                                                   int tid, f32x4 acc[4][4]) {
    const int lane = tid & 63;
    const int wv = tid >> 6;
    const int wm = wv >> 1, wn = wv & 1;
    const int col = lane & 15;
    const int quad = lane >> 4;
    const int row = tid >> 1;  // 0..127 staging row
    const int half = tid & 1;  // k-half: cols half*16..+16

    const size_t aoff = (size_t)(mBase + row) * E_ + half * 16;
    const size_t woff = (size_t)(nBase + row) * E_ + half * 16;

    uint4 wa0 = ((const uint4*)(Ab + aoff))[0];
    uint4 wa1 = ((const uint4*)(Ab + aoff))[1];
    uint4 wb0 = ((const uint4*)(Wb + woff))[0];
    uint4 wb1 = ((const uint4*)(Wb + woff))[1];

    for (int k0 = 0; k0 < E_; k0 += 32) {
        __syncthreads();  // previous step's readers done
        *(uint4*)&Als[row * 40 + half * 16] = wa0;
        *(uint4*)&Als[row * 40 + half * 16 + 8] = wa1;
        *(uint4*)&Bls[row * 40 + half * 16] = wb0;
        *(uint4*)&Bls[row * 40 + half * 16 + 8] = wb1;
        __syncthreads();
        if (k0 + 32 < E_) {  // prefetch next tile under this tile's compute
            wa0 = ((const uint4*)(Ab + aoff + k0 + 32))[0];
            wa1 = ((const uint4*)(Ab + aoff + k0 + 32))[1];
            wb0 = ((const uint4*)(Wb + woff + k0 + 32))[0];
            wb1 = ((const uint4*)(Wb + woff + k0 + 32))[1];
        }

        short8 bf[4];
#pragma unroll
        for (int tn = 0; tn < 4; ++tn)
            bf[tn] = *(const short8*)&Bls[(wn * 64 + tn * 16 + col) * 40 + quad * 8];
#pragma unroll
        for (int tm = 0; tm < 4; ++tm) {
            short8 af = *(const short8*)&Als[(wm * 64 + tm * 16 + col) * 40 + quad * 8];
#pragma unroll
            for (int tn = 0; tn < 4; ++tn)
                acc[tm][tn] =
                    __builtin_amdgcn_mfma_f32_16x16x32_bf16(af, bf[tn], acc[tm][tn], 0, 0, 0);
        }
    }
}

// ---------- generic GEMM core (f32 fallback paths, original structure) ----------
template <bool AB, bool WB>
__device__ __forceinline__ void mfma_gemm_body(unsigned short* Als, unsigned short* Bls,
                                               const unsigned short* Ab, const float* Af,
                                               const unsigned short* Wb, const float* Wf,
                                               int mBase, int nBase, int tid, f32x4 acc[4][4]) {
    const int lane = tid & 63;
    const int wv = tid >> 6;
    const int wm = wv >> 1, wn = wv & 1;
    const int col = lane & 15;
    const int quad = lane >> 4;
    const int row = tid >> 1;  // 0..127 staging row
    const int half = tid & 1;  // k-half: cols half*16..+16

    const size_t aoff = (size_t)(mBase + row) * E_ + half * 16;
    const size_t woff = (size_t)(nBase + row) * E_ + half * 16;

    for (int k0 = 0; k0 < E_; k0 += 32) {
        uint4 wa0, wa1, wb0, wb1;
        if (AB) {
            const uint4* s = (const uint4*)(Ab + aoff + k0);
            wa0 = s[0];
            wa1 = s[1];
        } else {
            const float4* s = (const float4*)(Af + aoff + k0);
            float4 f0 = s[0], f1 = s[1], f2 = s[2], f3 = s[3];
            wa0.x = pkbf(f0.x, f0.y); wa0.y = pkbf(f0.z, f0.w);
            wa0.z = pkbf(f1.x, f1.y); wa0.w = pkbf(f1.z, f1.w);
            wa1.x = pkbf(f2.x, f2.y); wa1.y = pkbf(f2.z, f2.w);
            wa1.z = pkbf(f3.x, f3.y); wa1.w = pkbf(f3.z, f3.w);
        }
        if (WB) {
            const uint4* s = (const uint4*)(Wb + woff + k0);
            wb0 = s[0];
            wb1 = s[1];
        } else {
            const float4* s = (const float4*)(Wf + woff + k0);
            float4 f0 = s[0], f1 = s[1], f2 = s[2], f3 = s[3];
            wb0.x = pkbf(f0.x, f0.y); wb0.y = pkbf(f0.z, f0.w);
            wb0.z = pkbf(f1.x, f1.y); wb0.w = pkbf(f1.z, f1.w);
            wb1.x = pkbf(f2.x, f2.y); wb1.y = pkbf(f2.z, f2.w);
            wb1.z = pkbf(f3.x, f3.y); wb1.w = pkbf(f3.z, f3.w);
        }
        __syncthreads();  // previous step's readers done
        *(uint4*)&Als[row * 40 + half * 16] = wa0;
        *(uint4*)&Als[row * 40 + half * 16 + 8] = wa1;
        *(uint4*)&Bls[row * 40 + half * 16] = wb0;
        *(uint4*)&Bls[row * 40 + half * 16 + 8] = wb1;
        __syncthreads();

        short8 bf[4];
#pragma unroll
        for (int tn = 0; tn < 4; ++tn)
            bf[tn] = *(const short8*)&Bls[(wn * 64 + tn * 16 + col) * 40 + quad * 8];
#pragma unroll
        for (int tm = 0; tm < 4; ++tm) {
            short8 af = *(const short8*)&Als[(wm * 64 + tm * 16 + col) * 40 + quad * 8];
#pragma unroll
            for (int tn = 0; tn < 4; ++tn)
                acc[tm][tn] =
                    __builtin_amdgcn_mfma_f32_16x16x32_bf16(af, bf[tn], acc[tm][tn], 0, 0, 0);
        }
    }
}

// ---------- proj epilogue (shared) ----------
__device__ __forceinline__ void proj_store(f32x4 acc[4][4], unsigned short* C, float scale,
                                           int mBase, int nBase, int tid) {
    const int lane = tid & 63;
    const int wv = tid >> 6;
    const int wm = wv >> 1, wn = wv & 1;
    const int col = lane & 15;
    const int quad = lane >> 4;
#pragma unroll
    for (int tm = 0; tm < 4; ++tm) {
#pragma unroll
        for (int r = 0; r < 4; ++r) {
            const int m = mBase + wm * 64 + tm * 16 + quad * 4 + r;
            const int b = m >> 11, t = m & (T_ - 1);
#pragma unroll
            for (int tn = 0; tn < 4; ++tn) {
                const int f = nBase + wn * 64 + tn * 16 + col;
                const int h = f >> 6, d = f & 63;
                C[(((size_t)(b * H_ + h)) * T_ + t) * D_ + d] = f2bf(acc[tm][tn][r] * scale);
            }
        }
    }
}

// ---------- projections (bf16 pre-converted path) ----------
__global__ __launch_bounds__(256) void proj_b16_kernel(
    const unsigned short* __restrict__ nyb, const unsigned short* __restrict__ xb,
    const unsigned short* __restrict__ Wq1, const unsigned short* __restrict__ Wk1,
    const unsigned short* __restrict__ Wq2, const unsigned short* __restrict__ Wk2,
    const unsigned short* __restrict__ Wv, unsigned short* __restrict__ q1,
    unsigned short* __restrict__ k1, unsigned short* __restrict__ q2,
    unsigned short* __restrict__ k2, unsigned short* __restrict__ v) {
    __shared__ __align__(16) unsigned short Als[128 * 40];
    __shared__ __align__(16) unsigned short Bls[128 * 40];
    const int tid = threadIdx.x;
    const int mBase = blockIdx.y << 7, nBase = blockIdx.x << 7;

    const unsigned short* A;
    const unsigned short* W;
    unsigned short* C;
    float scale = 1.0f;
    switch (blockIdx.z) {
        case 0: A = nyb; W = Wq1; C = q1; scale = QSCALE_LOG2E; break;
        case 1: A = nyb; W = Wk1; C = k1; break;
        case 2: A = xb;  W = Wq2; C = q2; scale = QSCALE_LOG2E; break;
        case 3: A = xb;  W = Wk2; C = k2; break;
        default: A = nyb; W = Wv; C = v; break;
    }
    f32x4 acc[4][4];
#pragma unroll
    for (int i = 0; i < 4; ++i)
#pragma unroll
        for (int j = 0; j < 4; ++j) acc[i][j] = (f32x4){0.f, 0.f, 0.f, 0.f};
    mfma_gemm_body_b16(Als, Bls, A, W, mBase, nBase, tid, acc);
    proj_store(acc, C, scale, mBase, nBase, tid);
}

// ---------- projections (f32 fallback path) ----------
__global__ __launch_bounds__(256) void proj_f32_kernel(
    const float* __restrict__ noisy_y, const float* __restrict__ x,
    const float* __restrict__ Wq1, const float* __restrict__ Wk1, const float* __restrict__ Wq2,
    const float* __restrict__ Wk2, const float* __restrict__ Wv, unsigned short* __restrict__ q1,
    unsigned short* __restrict__ k1, unsigned short* __restrict__ q2,
    unsigned short* __restrict__ k2, unsigned short* __restrict__ v) {
    __shared__ __align__(16) unsigned short Als[128 * 40];
    __shared__ __align__(16) unsigned short Bls[128 * 40];
    const int tid = threadIdx.x;
    const int mBase = blockIdx.y << 7, nBase = blockIdx.x << 7;

    const float* A;
    const float* W;
    unsigned short* C;
    float scale = 1.0f;
    switch (blockIdx.z) {
        case 0: A = noisy_y; W = Wq1; C = q1; scale = QSCALE_LOG2E; break;
        case 1: A = noisy_y; W = Wk1; C = k1; break;
        case 2: A = x;       W = Wq2; C = q2; scale = QSCALE_LOG2E; break;
        case 3: A = x;       W = Wk2; C = k2; break;
        default: A = noisy_y; W = Wv; C = v; break;
    }
    f32x4 acc[4][4];
#pragma unroll
    for (int i = 0; i < 4; ++i)
#pragma unroll
        for (int j = 0; j < 4; ++j) acc[i][j] = (f32x4){0.f, 0.f, 0.f, 0.f};
    mfma_gemm_body<false, false>(Als, Bls, nullptr, A, nullptr, W, mBase, nBase, tid, acc);
    proj_store(acc, C, scale, mBase, nBase, tid);
}

// ---------- output projection (two W variants) ----------
__device__ __forceinline__ void out_store(f32x4 acc[4][4], float* out, int mBase, int nBase,
                                          int tid) {
    const int lane = tid & 63;
    const int wv = tid >> 6;
    const int wm = wv >> 1, wn = wv & 1;
    const int col = lane & 15;
    const int quad = lane >> 4;
#pragma unroll
    for (int tm = 0; tm < 4; ++tm)
#pragma unroll
        for (int r = 0; r < 4; ++r) {
            const int m = mBase + wm * 64 + tm * 16 + quad * 4 + r;
#pragma unroll
            for (int tn = 0; tn < 4; ++tn)
                out[(size_t)m * E_ + nBase + wn * 64 + tn * 16 + col] = acc[tm][tn][r];
        }
}

__global__ __launch_bounds__(256) void out_b16_kernel(const unsigned short* __restrict__ attn,
                                                      const unsigned short* __restrict__ Woutb,
                                                      float* __restrict__ out) {
    __shared__ __align__(16) unsigned short Als[128 * 40];
    __shared__ __align__(16) unsigned short Bls[128 * 40];
    const int tid = threadIdx.x;
    const int mBase = blockIdx.y << 7, nBase = blockIdx.x << 7;
    f32x4 acc[4][4];
#pragma unroll
    for (int i = 0; i < 4; ++i)
#pragma unroll
        for (int j = 0; j < 4; ++j) acc[i][j] = (f32x4){0.f, 0.f, 0.f, 0.f};
    mfma_gemm_body_b16(Als, Bls, attn, Woutb, mBase, nBase, tid, acc);
    out_store(acc, out, mBase, nBase, tid);
}

__global__ __launch_bounds__(256) void out_f32_kernel(const unsigned short* __restrict__ attn,
                                                      const float* __restrict__ Wout,
                                                      float* __restrict__ out) {
    __shared__ __align__(16) unsigned short Als[128 * 40];
    __shared__ __align__(16) unsigned short Bls[128 * 40];
    const int tid = threadIdx.x;
    const int mBase = blockIdx.y << 7, nBase = blockIdx.x << 7;
    f32x4 acc[4][4];
#pragma unroll
    for (int i = 0; i < 4; ++i)
#pragma unroll
        for (int j = 0; j < 4; ++j) acc[i][j] = (f32x4){0.f, 0.f, 0.f, 0.f};
    mfma_gemm_body<true, false>(Als, Bls, attn, nullptr, nullptr, Wout, mBase, nBase, tid, acc);
    out_store(acc, out, mBase, nBase, tid);
}

// ---------- lambda scalar ----------
__global__ void lambda_kernel(const float* __restrict__ lq1, const float* __restrict__ lk1,
                              const float* __restrict__ lq2, const float* __restrict__ lk2,
                              float* __restrict__ lam) {
    const int l = threadIdx.x;  // 64
    float s1 = lq1[l] * lk1[l];
    float s2 = lq2[l] * lk2[l];
#pragma unroll
    for (int off = 32; off; off >>= 1) {
        s1 += __shfl_xor(s1, off, 64);
        s2 += __shfl_xor(s2, off, 64);
    }
    if (l == 0) lam[0] = expf(s1) - expf(s2) + LAMBDA_INIT_F;
}

// prefetch loads for one K/V tile into NAMED scalars (GEMM-proven cross-barrier
// shape: named uint4/uint2 only -- arrays/lambda-captures demote to scratch).
#define LOAD_KV(KT)                                                                        \
    {                                                                                      \
        const uint4* p1_ = (const uint4*)(k1g + base + (size_t)((KT) + kr) * D_ + dd);     \
        const uint4* p2_ = (const uint4*)(k2g + base + (size_t)((KT) + kr) * D_ + dd);     \
        k1a = p1_[0]; k1b = p1_[1]; k1c = p1_[2]; k1d = p1_[3];                            \
        k2a = p2_[0]; k2b = p2_[1]; k2c = p2_[2]; k2d = p2_[3];                            \
        const unsigned short* vp_ = vg + base + (size_t)((KT) + vR0) * D_ + vd0;           \
        vr0 = *(const uint2*)(vp_);                                                        \
        vr1 = *(const uint2*)(vp_ + D_);                                                   \
        vr2 = *(const uint2*)(vp_ + 2 * D_);                                               \
        vr3 = *(const uint2*)(vp_ + 3 * D_);                                               \
        vs0 = *(const uint2*)(vp_ + 16 * D_);                                              \
        vs1 = *(const uint2*)(vp_ + 17 * D_);                                              \
        vs2 = *(const uint2*)(vp_ + 18 * D_);                                              \
        vs3 = *(const uint2*)(vp_ + 19 * D_);                                              \
    }

// ---------- MFMA flash attention: 128 thr = 2 waves, 64 q-rows ----------
// Round-13 = round-6/12 optimum (attn 120.5 us, total 208.4 us) with ONE local
// change: P-pack uses v_cvt_pk_bf16_f32 (1 instr) instead of pkbf (3 VALU instr)
// -- removes ~32 VALU ops/kstep/wave from the busiest pipe (VALUBusy 41%).
// Register pressure neutral-to-lower (pkbf's add-temps disappear), so the
// VGPR=128 <-> 4 blocks/CU edge (the active constraint, r10/r11 forensics)
// should hold. All structure otherwise verbatim.
// Gates: VGPR <= 128, WRITE_SIZE ~8.2 MB, absmax <= 3.36e-2.
__global__ __launch_bounds__(128) void attn_mfma_kernel(
    const unsigned short* __restrict__ q1g, const unsigned short* __restrict__ k1g,
    const unsigned short* __restrict__ q2g, const unsigned short* __restrict__ k2g,
    const unsigned short* __restrict__ vg, const float* __restrict__ lamp,
    const float* __restrict__ subln, unsigned short* __restrict__ attn_out) {
    __shared__ __align__(16) unsigned short Ks1[64 * 72];
    __shared__ __align__(16) unsigned short Ks2[64 * 72];
    __shared__ __align__(16) unsigned short Vt[64 * 72];  // V^T: [d][virtual key]

    const int tid = threadIdx.x;
    const int lane = tid & 63;
    const int wv = tid >> 6;  // 0..1
    const int col = lane & 15;
    const int quad = lane >> 4;

    // XCD-aware remap (bijective on 1024 wgs; affects locality only, not correctness)
    const int wg = blockIdx.x + (int)blockIdx.y * (T_ / 64) + (int)blockIdx.z * (T_ / 64) * H_;
    const int xcd = wg & 7, local = wg >> 3;
    const int grp = xcd * 4 + (local >> 5);  // 0..31 = (b,h) group
    const int qt = local & 31;               // q-tile within group
    const int h = grp & (H_ - 1), b = grp >> 4;
    const size_t base = ((size_t)(b * H_ + h)) * T_ * D_;
    const int qBase = qt << 6;  // 64 q-rows per block
    const float lam = lamp[0];

    // staging geometry
    const int kr = tid >> 1;          // K row 0..63
    const int dd = (tid & 1) << 5;    // K dim half 0/32
    const int vu = tid & 7;           // V virtual-key octet
    const int vd0 = (tid >> 3) << 2;  // V dim group 0..60
    const int vR0 = 32 * (vu >> 2) + 4 * (vu & 3);  // first real key row

    // Q B-fragments for both q-sets (resident all k-steps)
    short8 Qa1[2][2], Qa2[2][2];
#pragma unroll
    for (int s = 0; s < 2; ++s) {
        const int qRow = qBase + wv * 32 + s * 16 + col;
        const unsigned short* p1 = q1g + base + (size_t)qRow * D_ + quad * 8;
        const unsigned short* p2 = q2g + base + (size_t)qRow * D_ + quad * 8;
        Qa1[s][0] = *(const short8*)p1;
        Qa1[s][1] = *(const short8*)(p1 + 32);
        Qa2[s][0] = *(const short8*)p2;
        Qa2[s][1] = *(const short8*)(p2 + 32);
    }

    f32x4 O1[2][4], O2[2][4];
#pragma unroll
    for (int s = 0; s < 2; ++s)
#pragma unroll
        for (int n = 0; n < 4; ++n) {
            O1[s][n] = (f32x4){0.f, 0.f, 0.f, 0.f};
            O2[s][n] = (f32x4){0.f, 0.f, 0.f, 0.f};
        }
    float ls1[2] = {0.f, 0.f}, ls2[2] = {0.f, 0.f};

    // named prefetch registers (cross barriers -- must stay scalars, no arrays)
    uint4 k1a, k1b, k1c, k1d, k2a, k2b, k2c, k2d;
    uint2 vr0, vr1, vr2, vr3, vs0, vs1, vs2, vs3;
    LOAD_KV(0);  // prologue prefetch

    for (int kt = 0; kt < T_; kt += 64) {
        __syncthreads();  // previous step's readers done
        {  // LDS-write phase: consume the prefetched named regs
            uint4* d1 = (uint4*)&Ks1[kr * 72 + dd];
            uint4* d2 = (uint4*)&Ks2[kr * 72 + dd];
            d1[0] = k1a; d1[1] = k1b; d1[2] = k1c; d1[3] = k1d;
            d2[0] = k2a; d2[1] = k2b; d2[2] = k2c; d2[3] = k2d;
            uint4 o;
            o.x = pklo(vr0.x, vr1.x); o.y = pklo(vr2.x, vr3.x);
            o.z = pklo(vs0.x, vs1.x); o.w = pklo(vs2.x, vs3.x);
            *(uint4*)&Vt[(vd0 + 0) * 72 + 8 * vu] = o;
            o.x = pkhi(vr0.x, vr1.x); o.y = pkhi(vr2.x, vr3.x);
            o.z = pkhi(vs0.x, vs1.x); o.w = pkhi(vs2.x, vs3.x);
            *(uint4*)&Vt[(vd0 + 1) * 72 + 8 * vu] = o;
            o.x = pklo(vr0.y, vr1.y); o.y = pklo(vr2.y, vr3.y);
            o.z = pklo(vs0.y, vs1.y); o.w = pklo(vs2.y, vs3.y);
            *(uint4*)&Vt[(vd0 + 2) * 72 + 8 * vu] = o;
            o.x = pkhi(vr0.y, vr1.y); o.y = pkhi(vr2.y, vr3.y);
            o.z = pkhi(vs0.y, vs1.y); o.w = pkhi(vs2.y, vs3.y);
            *(uint4*)&Vt[(vd0 + 3) * 72 + 8 * vu] = o;
        }
        __syncthreads();
        if (kt + 64 < T_) LOAD_KV(kt + 64);  // latency hides under compute below
        __builtin_amdgcn_s_setprio(1);

        unsigned int paU[2][2][4];  // [s][chunk][word], kstep scope, shared mat1/mat2

        {  // ---- matrix 1: QK -> exp2 -> in-register P (cvt_pk) -> PV ----
#pragma unroll
            for (int t = 0; t < 4; ++t) {
                const int ro = (t * 16 + col) * 72 + quad * 8;
                const f32x4 z = {0.f, 0.f, 0.f, 0.f};
                short8 a0 = *(const short8*)&Ks1[ro];
                short8 a1 = *(const short8*)&Ks1[ro + 32];
#pragma unroll
                for (int s = 0; s < 2; ++s) {
                    f32x4 S = __builtin_amdgcn_mfma_f32_16x16x32_bf16(a0, Qa1[s][0], z, 0, 0, 0);
                    S = __builtin_amdgcn_mfma_f32_16x16x32_bf16(a1, Qa1[s][1], S, 0, 0, 0);
                    const float p0 = fexp2(S[0]), p1 = fexp2(S[1]);
                    const float p2 = fexp2(S[2]), p3 = fexp2(S[3]);
                    ls1[s] += (p0 + p1) + (p2 + p3);
                    paU[s][t >> 1][(t & 1) * 2] = cvtpk(p0, p1);
                    paU[s][t >> 1][(t & 1) * 2 + 1] = cvtpk(p2, p3);
                }
            }
#pragma unroll
            for (int c = 0; c < 2; ++c) {
                short8 vf[4];
#pragma unroll
                for (int n = 0; n < 4; ++n)
                    vf[n] = *(const short8*)&Vt[(n * 16 + col) * 72 + c * 32 + quad * 8];
#pragma unroll
                for (int s = 0; s < 2; ++s) {
                    union { unsigned int u[4]; short8 s8; } pp;
#pragma unroll
                    for (int w = 0; w < 4; ++w) pp.u[w] = paU[s][c][w];
#pragma unroll
                    for (int n = 0; n < 4; ++n)
                        O1[s][n] = __builtin_amdgcn_mfma_f32_16x16x32_bf16(pp.s8, vf[n],
                                                                           O1[s][n], 0, 0, 0);
                }
            }
        }
        {  // ---- matrix 2 ----
#pragma unroll
            for (int t = 0; t < 4; ++t) {
                const int ro = (t * 16 + col) * 72 + quad * 8;
                const f32x4 z = {0.f, 0.f, 0.f, 0.f};
                short8 a0 = *(const short8*)&Ks2[ro];
                short8 a1 = *(const short8*)&Ks2[ro + 32];
#pragma unroll
                for (int s = 0; s < 2; ++s) {
                    f32x4 S = __builtin_amdgcn_mfma_f32_16x16x32_bf16(a0, Qa2[s][0], z, 0, 0, 0);
                    S = __builtin_amdgcn_mfma_f32_16x16x32_bf16(a1, Qa2[s][1], S, 0, 0, 0);
                    const float p0 = fexp2(S[0]), p1 = fexp2(S[1]);
                    const float p2 = fexp2(S[2]), p3 = fexp2(S[3]);
                    ls2[s] += (p0 + p1) + (p2 + p3);
                    paU[s][t >> 1][(t & 1) * 2] = cvtpk(p0, p1);
                    paU[s][t >> 1][(t & 1) * 2 + 1] = cvtpk(p2, p3);
                }
            }
#pragma unroll
            for (int c = 0; c < 2; ++c) {
                short8 vf[4];
#pragma unroll
                for (int n = 0; n < 4; ++n)
                    vf[n] = *(const short8*)&Vt[(n * 16 + col) * 72 + c * 32 + quad * 8];
#pragma unroll
                for (int s = 0; s < 2; ++s) {
                    union { unsigned int u[4]; short8 s8; } pp;
#pragma unroll
                    for (int w = 0; w < 4; ++w) pp.u[w] = paU[s][c][w];
#pragma unroll
                    for (int n = 0; n < 4; ++n)
                        O2[s][n] = __builtin_amdgcn_mfma_f32_16x16x32_bf16(pp.s8, vf[n],
                                                                           O2[s][n], 0, 0, 0);
                }
            }
        }
        __builtin_amdgcn_s_setprio(0);
    }

    // epilogue: per-q softmax denominators, combine, RMSNorm, affine, store bf16 [B,T,H,D]
#pragma unroll
    for (int s = 0; s < 2; ++s) {
        float s1 = ls1[s];
        s1 += __shfl_xor(s1, 16, 64);
        s1 += __shfl_xor(s1, 32, 64);
        float s2 = ls2[s];
        s2 += __shfl_xor(s2, 16, 64);
        s2 += __shfl_xor(s2, 32, 64);
        float il1[4], il2[4];
#pragma unroll
        for (int r = 0; r < 4; ++r) {
            il1[r] = 1.0f / __shfl(s1, quad * 4 + r, 64);
            il2[r] = lam / __shfl(s2, quad * 4 + r, 64);
        }
        float acc[4][4];
        float ssq[4] = {0.f, 0.f, 0.f, 0.f};
#pragma unroll
        for (int n = 0; n < 4; ++n)
#pragma unroll
            for (int r = 0; r < 4; ++r) {
                const float v = O1[s][n][r] * il1[r] - O2[s][n][r] * il2[r];
                acc[n][r] = v;
                ssq[r] += v * v;
            }
#pragma unroll
        for (int r = 0; r < 4; ++r) {
            float sv = ssq[r];
            sv += __shfl_xor(sv, 1, 64); sv += __shfl_xor(sv, 2, 64);
            sv += __shfl_xor(sv, 4, 64); sv += __shfl_xor(sv, 8, 64);
            ssq[r] = rsqrtf(sv * (1.0f / 64.0f) + EPS_) * (1.0f - LAMBDA_INIT_F);
        }
#pragma unroll
        for (int n = 0; n < 4; ++n) {
            const float sw = subln[n * 16 + col];
#pragma unroll
            for (int r = 0; r < 4; ++r) {
                const int row = qBase + wv * 32 + s * 16 + quad * 4 + r;
                attn_out[((size_t)(b * T_ + row) * H_ + h) * D_ + n * 16 + col] =
                    f2bf(acc[n][r] * ssq[r] * sw);
            }
        }
    }
}

extern "C" void kernel_launch(void* const* d_in, const int* in_sizes, int n_in, void* d_out,
                              int out_size, void* d_ws, size_t ws_size, hipStream_t stream) {
    const float* noisy_y = (const float*)d_in[0];
    const float* x = (const float*)d_in[1];
    const float* Wq1 = (const float*)d_in[2];
    const float* Wk1 = (const float*)d_in[3];
    const float* Wq2 = (const float*)d_in[4];
    const float* Wk2 = (const float*)d_in[5];
    const float* Wv = (const float*)d_in[6];
    const float* Wout = (const float*)d_in[7];
    const float* lq1 = (const float*)d_in[8];
    const float* lk1 = (const float*)d_in[9];
    const float* lq2 = (const float*)d_in[10];
    const float* lk2 = (const float*)d_in[11];
    const float* subln = (const float*)d_in[12];
    float* out = (float*)d_out;  // reference output dtype is float32

    const size_t SZ = (size_t)B_ * H_ * T_ * D_;  // 4 Mi elements
    const size_t WSZ = (size_t)E_ * E_;           // 1 Mi elements
    const size_t need = 64 + 6 * SZ * sizeof(unsigned short);                       // ~48 MiB
    const size_t need_full = need + (2 * SZ + 6 * WSZ) * sizeof(unsigned short);    // ~76 MiB
    if (ws_size < need) {
        return;  // diagnostic signature: zero output -> error 1.6797
    }
    float* lamv = (float*)d_ws;
    unsigned short* q1 = (unsigned short*)((char*)d_ws + 64);
    unsigned short* k1 = q1 + SZ;
    unsigned short* q2 = k1 + SZ;
    unsigned short* k2 = q2 + SZ;
    unsigned short* v = k2 + SZ;
    unsigned short* attn_out = v + SZ;  // [B,T,H,D] bf16

    lambda_kernel<<<1, 64, 0, stream>>>(lq1, lk1, lq2, lk2, lamv);

    if (ws_size >= need_full) {
        unsigned short* nyb = attn_out + SZ;
        unsigned short* xb = nyb + SZ;
        unsigned short* wq1b = xb + SZ;
        unsigned short* wk1b = wq1b + WSZ;
        unsigned short* wq2b = wk1b + WSZ;
        unsigned short* wk2b = wq2b + WSZ;
        unsigned short* wvb = wk2b + WSZ;
        unsigned short* woutb = wvb + WSZ;
        conv_kernel<<<dim3(1024, 8, 1), 256, 0, stream>>>(noisy_y, x, Wq1, Wk1, Wq2, Wk2, Wv,
                                                          Wout, nyb, xb, wq1b, wk1b, wq2b, wk2b,
                                                          wvb, woutb);
        proj_b16_kernel<<<dim3(E_ / 128, M_ / 128, 5), 256, 0, stream>>>(
            nyb, xb, wq1b, wk1b, wq2b, wk2b, wvb, q1, k1, q2, k2, v);
        attn_mfma_kernel<<<dim3(T_ / 64, H_, B_), 128, 0, stream>>>(q1, k1, q2, k2, v, lamv,
                                                                    subln, attn_out);
        out_b16_kernel<<<dim3(E_ / 128, M_ / 128, 1), 256, 0, stream>>>(attn_out, woutb, out);
    } else {
        proj_f32_kernel<<<dim3(E_ / 128, M_ / 128, 5), 256, 0, stream>>>(
            noisy_y, x, Wq1, Wk1, Wq2, Wk2, Wv, q1, k1, q2, k2, v);
        attn_mfma_kernel<<<dim3(T_ / 64, H_, B_), 128, 0, stream>>>(q1, k1, q2, k2, v, lamv,
                                                                    subln, attn_out);
        out_f32_kernel<<<dim3(E_ / 128, M_ / 128, 1), 256, 0, stream>>>(attn_out, Wout, out);
    }
}